// Round 4
// baseline (122.408 us; speedup 1.0000x reference)
//
#include <hip/hip_runtime.h>
#include <hip/hip_bf16.h>

#define BB 2
#define SS 1024
#define DD 1024
#define HH 16
#define HDD 64
#define MASK_VAL -10000.0f
#define BSD (BB * SS * DD)   // 2097152

typedef __attribute__((ext_vector_type(8))) short bf16x8;
typedef __attribute__((ext_vector_type(4))) short short4v;
typedef __attribute__((ext_vector_type(4))) float f32x4;

__device__ __forceinline__ short f2bf(float f) {
    union { float f; unsigned u; } v; v.f = f;
    unsigned r = v.u + 0x7FFFu + ((v.u >> 16) & 1u);   // RN-even
    return (short)(r >> 16);
}

// ---------------------------------------------------------------------------
// x_bf = bf16(h[0] + h[1])
// ---------------------------------------------------------------------------
__global__ __launch_bounds__(256) void k_prep_x(const float* __restrict__ h,
                                                short* __restrict__ xbf) {
    int i = blockIdx.x * blockDim.x + threadIdx.x;
    const float4* h0 = (const float4*)h;
    const float4* h1 = (const float4*)(h + (size_t)BSD);
    float4 a0 = h0[2 * i], a1 = h0[2 * i + 1];
    float4 b0 = h1[2 * i], b1 = h1[2 * i + 1];
    bf16x8 o;
    o[0] = f2bf(a0.x + b0.x); o[1] = f2bf(a0.y + b0.y);
    o[2] = f2bf(a0.z + b0.z); o[3] = f2bf(a0.w + b0.w);
    o[4] = f2bf(a1.x + b1.x); o[5] = f2bf(a1.y + b1.y);
    o[6] = f2bf(a1.z + b1.z); o[7] = f2bf(a1.w + b1.w);
    ((bf16x8*)xbf)[i] = o;
}

__global__ __launch_bounds__(256) void k_prep_w(const float* __restrict__ wq,
                                                const float* __restrict__ wk,
                                                const float* __restrict__ wv,
                                                const float* __restrict__ wo,
                                                short* __restrict__ wbf) {
    int z = blockIdx.z;
    const float* src = (z == 0) ? wq : (z == 1) ? wk : (z == 2) ? wv : wo;
    short* dst = wbf + (size_t)z * (DD * DD);
    int i = blockIdx.x * blockDim.x + threadIdx.x;
    const float4* s4 = (const float4*)src;
    float4 a0 = s4[2 * i], a1 = s4[2 * i + 1];
    bf16x8 o;
    o[0] = f2bf(a0.x); o[1] = f2bf(a0.y); o[2] = f2bf(a0.z); o[3] = f2bf(a0.w);
    o[4] = f2bf(a1.x); o[5] = f2bf(a1.y); o[6] = f2bf(a1.z); o[7] = f2bf(a1.w);
    ((bf16x8*)dst)[i] = o;
}

// ---------------------------------------------------------------------------
// bf16 MFMA GEMM, 128x128 tile, BK=32. epi: 0 = f32 out (+bias),
// 1 = bf16 out [B,S,D] (+bias), 2 = bf16 V^T out [B,H,64,S] (+bias).
// ---------------------------------------------------------------------------
#define TM 128
#define TN 128
#define TK 32

__device__ __forceinline__ void gemm_bf16_body(const short* __restrict__ A,
                                               const short* __restrict__ W,
                                               const float* __restrict__ bias,
                                               float* __restrict__ Cf,
                                               short* __restrict__ Cb,
                                               int epi, int K, int N,
                                               int bm, int bn) {
    __shared__ __align__(16) short As[TM * TK];
    __shared__ __align__(16) short Bs[TN * TK];
    const int tid = threadIdx.x;
    const int lane = tid & 63;
    const int wid = tid >> 6;
    const int wm = wid >> 1;
    const int wn = wid & 1;
    const int lr = lane & 15;
    const int kq = lane >> 4;

    f32x4 acc[4][4];
#pragma unroll
    for (int i = 0; i < 4; ++i)
#pragma unroll
        for (int j = 0; j < 4; ++j) acc[i][j] = (f32x4)0.0f;

    for (int k0 = 0; k0 < K; k0 += TK) {
#pragma unroll
        for (int i = 0; i < 2; ++i) {
            int t = i * 256 + tid;
            int r = t >> 2;
            int kk = (t & 3) << 3;
            const short* ga = A + (size_t)(bm + r) * K + k0 + kk;
            __builtin_amdgcn_global_load_lds(
                (const __attribute__((address_space(1))) unsigned*)ga,
                (__attribute__((address_space(3))) unsigned*)&As[t * 8], 16, 0, 0);
            const short* gb = W + (size_t)(bn + r) * K + k0 + kk;
            __builtin_amdgcn_global_load_lds(
                (const __attribute__((address_space(1))) unsigned*)gb,
                (__attribute__((address_space(3))) unsigned*)&Bs[t * 8], 16, 0, 0);
        }
        __syncthreads();

        bf16x8 af[4], bfr[4];
#pragma unroll
        for (int f = 0; f < 4; ++f) {
            af[f]  = *(const bf16x8*)&As[(wm * 64 + f * 16 + lr) * TK + kq * 8];
            bfr[f] = *(const bf16x8*)&Bs[(wn * 64 + f * 16 + lr) * TK + kq * 8];
        }
#pragma unroll
        for (int fm = 0; fm < 4; ++fm)
#pragma unroll
            for (int fn = 0; fn < 4; ++fn)
                acc[fm][fn] = __builtin_amdgcn_mfma_f32_16x16x32_bf16(
                    af[fm], bfr[fn], acc[fm][fn], 0, 0, 0);
        __syncthreads();
    }

    // epilogue. C/D layout: col = lane&15, row = (lane>>4)*4 + reg.
#pragma unroll
    for (int fm = 0; fm < 4; ++fm) {
        int row0 = bm + wm * 64 + fm * 16 + kq * 4;
#pragma unroll
        for (int fn = 0; fn < 4; ++fn) {
            int col = bn + wn * 64 + fn * 16 + lr;
            float bv = bias[col];
            if (epi == 0) {
#pragma unroll
                for (int j = 0; j < 4; ++j)
                    Cf[(size_t)(row0 + j) * N + col] = acc[fm][fn][j] + bv;
            } else if (epi == 1) {
#pragma unroll
                for (int j = 0; j < 4; ++j)
                    Cb[(size_t)(row0 + j) * N + col] = f2bf(acc[fm][fn][j] + bv);
            } else {
                // V^T: [B][H][64][S]; rows row0..row0+3 are contiguous in S
                int bidx = row0 >> 10, s0 = row0 & 1023;
                size_t addr = ((size_t)(bidx * HH + (col >> 6)) * HDD + (col & 63)) * SS + s0;
                short4v o;
                o.x = f2bf(acc[fm][fn][0] + bv); o.y = f2bf(acc[fm][fn][1] + bv);
                o.z = f2bf(acc[fm][fn][2] + bv); o.w = f2bf(acc[fm][fn][3] + bv);
                *(short4v*)&Cb[addr] = o;
            }
        }
    }
}

__global__ __launch_bounds__(256) void k_gemm_qkv(
    const short* __restrict__ xbf, const short* __restrict__ wbf,
    const float* __restrict__ bq, const float* __restrict__ bk,
    const float* __restrict__ bv,
    short* __restrict__ qb, short* __restrict__ kb, short* __restrict__ vt) {
    int z = blockIdx.z;
    const short* W = wbf + (size_t)z * (DD * DD);
    const float* bias = (z == 0) ? bq : (z == 1) ? bk : bv;
    short* C = (z == 0) ? qb : (z == 1) ? kb : vt;
    int epi = (z == 2) ? 2 : 1;
    gemm_bf16_body(xbf, W, bias, nullptr, C, epi, DD, DD,
                   blockIdx.y * TM, blockIdx.x * TN);
}

__global__ __launch_bounds__(256) void k_gemm_out(
    const short* __restrict__ A, const short* __restrict__ W,
    const float* __restrict__ bias, float* __restrict__ C) {
    gemm_bf16_body(A, W, bias, C, nullptr, 0, DD, DD,
                   blockIdx.y * TM, blockIdx.x * TN);
}

// ---------------------------------------------------------------------------
// MFMA flash attention, barrier-free: 4 INDEPENDENT waves per block, each
// owning 16 q-rows. K and V^T fragments are read directly from global (the
// per-head K/V slices are 128KB each -> L2/L1-resident; m169 lesson: staging
// L2-fit data is pure overhead). Only P transposes through per-wave LDS.
// Defer-max (T13) skips the O-rescale when max growth <= 8.
// ---------------------------------------------------------------------------
__global__ __launch_bounds__(256) void k_attn(
    const short* __restrict__ qb, const short* __restrict__ kb,
    const short* __restrict__ vt, const float* __restrict__ mask,
    short* __restrict__ ctx) {
    __shared__ __align__(16) short Pls[4][16 * 64];

    const int bh = blockIdx.y;
    const int b = bh >> 4;
    const int h = bh & 15;
    const int q0 = blockIdx.x << 6;
    const int tid = threadIdx.x;
    const int lane = tid & 63;
    const int w = tid >> 6;
    const int lr = lane & 15;
    const int kq = lane >> 4;
    const float scale = 0.125f;

    const short* khead = kb + (size_t)b * SS * DD + h * HDD;   // + kv*DD + d
    const short* vhead = vt + (size_t)bh * HDD * SS;           // + d*SS + kv
    const float* maskp = mask + b * SS;
    short* Pw = &Pls[w][0];

    // Q fragments (A-frag): row = lr, k-quarter kq
    bf16x8 qf[2];
    {
        const short* qrow = qb + ((size_t)(b * SS + q0 + w * 16 + lr)) * DD + h * HDD;
        qf[0] = *(const bf16x8*)(qrow + kq * 8);
        qf[1] = *(const bf16x8*)(qrow + 32 + kq * 8);
    }

    float m_r[4], l_r[4];
    f32x4 O[4];
#pragma unroll
    for (int j = 0; j < 4; ++j) { m_r[j] = -3.0e38f; l_r[j] = 0.f; O[j] = (f32x4)0.0f; }

    for (int t0 = 0; t0 < SS; t0 += 64) {
        // ---- issue all fragment loads up front (latency hides under the
        //      other waves' compute; vf not needed until PV) ----
        bf16x8 kf[4][2], vf[4][2];
#pragma unroll
        for (int fc = 0; fc < 4; ++fc) {
            const short* kr = khead + (size_t)(t0 + fc * 16 + lr) * DD + kq * 8;
            kf[fc][0] = *(const bf16x8*)kr;
            kf[fc][1] = *(const bf16x8*)(kr + 32);
        }
#pragma unroll
        for (int fd = 0; fd < 4; ++fd) {
            const short* vr = vhead + (size_t)(fd * 16 + lr) * SS + t0 + kq * 8;
            vf[fd][0] = *(const bf16x8*)vr;
            vf[fd][1] = *(const bf16x8*)(vr + 32);
        }
        float addv[4];
#pragma unroll
        for (int fc = 0; fc < 4; ++fc)
            addv[fc] = (1.0f - maskp[t0 + fc * 16 + lr]) * MASK_VAL;

        // ---- QK^T: S[q=kq*4+j][kv=fc*16+lr] ----
        f32x4 sacc[4];
#pragma unroll
        for (int fc = 0; fc < 4; ++fc) sacc[fc] = (f32x4)0.0f;
        __builtin_amdgcn_s_setprio(1);
#pragma unroll
        for (int fc = 0; fc < 4; ++fc) {
            sacc[fc] = __builtin_amdgcn_mfma_f32_16x16x32_bf16(qf[0], kf[fc][0], sacc[fc], 0, 0, 0);
            sacc[fc] = __builtin_amdgcn_mfma_f32_16x16x32_bf16(qf[1], kf[fc][1], sacc[fc], 0, 0, 0);
        }
        __builtin_amdgcn_s_setprio(0);

        float s[4][4];
#pragma unroll
        for (int fc = 0; fc < 4; ++fc)
#pragma unroll
            for (int j = 0; j < 4; ++j)
                s[fc][j] = sacc[fc][j] * scale + addv[fc];

        // ---- online softmax (rows replicated over the 16 kv-lanes) ----
        float rm[4];
#pragma unroll
        for (int j = 0; j < 4; ++j) {
            rm[j] = fmaxf(fmaxf(s[0][j], s[1][j]), fmaxf(s[2][j], s[3][j]));
#pragma unroll
            for (int mo = 1; mo < 16; mo <<= 1)
                rm[j] = fmaxf(rm[j], __shfl_xor(rm[j], mo, 16));
        }
        bool sk = (rm[0] <= m_r[0] + 8.0f) && (rm[1] <= m_r[1] + 8.0f) &&
                  (rm[2] <= m_r[2] + 8.0f) && (rm[3] <= m_r[3] + 8.0f);
        if (!__all(sk)) {
#pragma unroll
            for (int j = 0; j < 4; ++j) {
                float mn = fmaxf(m_r[j], rm[j]);
                float alpha = __expf(m_r[j] - mn);
                m_r[j] = mn;
                l_r[j] *= alpha;
#pragma unroll
                for (int fd = 0; fd < 4; ++fd) O[fd][j] *= alpha;
            }
        }
        float rs[4];
#pragma unroll
        for (int j = 0; j < 4; ++j) rs[j] = 0.f;
#pragma unroll
        for (int fc = 0; fc < 4; ++fc)
#pragma unroll
            for (int j = 0; j < 4; ++j) {
                float p = __expf(s[fc][j] - m_r[j]);
                s[fc][j] = p;
                rs[j] += p;
            }
#pragma unroll
        for (int j = 0; j < 4; ++j) {
#pragma unroll
            for (int mo = 1; mo < 16; mo <<= 1)
                rs[j] += __shfl_xor(rs[j], mo, 16);
            l_r[j] += rs[j];
        }

        // ---- P -> per-wave LDS (swizzled 128B rows), bf16 ----
#pragma unroll
        for (int fc = 0; fc < 4; ++fc) {
            int col = fc * 16 + lr;
#pragma unroll
            for (int j = 0; j < 4; ++j) {
                int q = kq * 4 + j;
                Pw[q * 64 + ((((col >> 3) ^ (q & 7)) << 3) | (col & 7))] = f2bf(s[fc][j]);
            }
        }
        asm volatile("s_waitcnt lgkmcnt(0)" ::: "memory");

        // ---- PV: O[q][d=fd*16+lr] += P[q][kv] * V[kv][d] ----
        bf16x8 pa[2];
        {
            int sw = lr & 7;
            pa[0] = *(const bf16x8*)&Pw[lr * 64 + ((kq ^ sw) << 3)];
            pa[1] = *(const bf16x8*)&Pw[lr * 64 + (((4 + kq) ^ sw) << 3)];
        }
        __builtin_amdgcn_s_setprio(1);
#pragma unroll
        for (int fd = 0; fd < 4; ++fd) {
            O[fd] = __builtin_amdgcn_mfma_f32_16x16x32_bf16(pa[0], vf[fd][0], O[fd], 0, 0, 0);
            O[fd] = __builtin_amdgcn_mfma_f32_16x16x32_bf16(pa[1], vf[fd][1], O[fd], 0, 0, 0);
        }
        __builtin_amdgcn_s_setprio(0);
    }

    // finalize + write ctx bf16 [B,S,D]
    short* cb = ctx + ((size_t)(b * SS + q0 + w * 16)) * DD + h * HDD;
#pragma unroll
    for (int j = 0; j < 4; ++j) {
        float inv = 1.0f / l_r[j];
        int qrow = kq * 4 + j;
#pragma unroll
        for (int fd = 0; fd < 4; ++fd)
            cb[(size_t)qrow * DD + fd * 16 + lr] = f2bf(O[fd][j] * inv);
    }
}

// ---------------------------------------------------------------------------
extern "C" void kernel_launch(void* const* d_in, const int* in_sizes, int n_in,
                              void* d_out, int out_size, void* d_ws, size_t ws_size,
                              hipStream_t stream) {
    const float* h    = (const float*)d_in[0];
    const float* mask = (const float*)d_in[1];
    const float* wq   = (const float*)d_in[2];
    const float* bq   = (const float*)d_in[3];
    const float* wk   = (const float*)d_in[4];
    const float* bk   = (const float*)d_in[5];
    const float* wv   = (const float*)d_in[6];
    const float* bv   = (const float*)d_in[7];
    const float* wo   = (const float*)d_in[8];
    const float* bo   = (const float*)d_in[9];
    float* out = (float*)d_out;

    char* base = (char*)d_ws;
    short* x_bf  = (short*)base;                       // 4 MB
    short* w_bf  = (short*)(base + (4u << 20));        // 8 MB
    short* q_bf  = (short*)(base + (12u << 20));       // 4 MB
    short* k_bf  = (short*)(base + (16u << 20));       // 4 MB
    short* v_t   = (short*)(base + (20u << 20));       // 4 MB
    short* ctxbf = (short*)(base + (24u << 20));       // 4 MB

    k_prep_x<<<BSD / 8 / 256, 256, 0, stream>>>(h, x_bf);
    k_prep_w<<<dim3(DD * DD / 8 / 256, 1, 4), 256, 0, stream>>>(wq, wk, wv, wo, w_bf);

    dim3 gqkv(DD / TN, BB * SS / TM, 3);
    k_gemm_qkv<<<gqkv, 256, 0, stream>>>(x_bf, w_bf, bq, bk, bv, q_bf, k_bf, v_t);

    dim3 gattn(SS / 64, BB * HH);
    k_attn<<<gattn, 256, 0, stream>>>(q_bf, k_bf, v_t, mask, ctxbf);

    dim3 gout(DD / TN, BB * SS / TM);
    k_gemm_out<<<gout, 256, 0, stream>>>(ctxbf, w_bf + (size_t)3 * DD * DD, bo, out);
}

// Round 5
// 102.595 us; speedup vs baseline: 1.1931x; 1.1931x over previous
//
#include <hip/hip_runtime.h>
#include <hip/hip_bf16.h>

#define BB 2
#define SS 1024
#define DD 1024
#define HH 16
#define HDD 64
#define MASK_VAL -10000.0f
#define BSD (BB * SS * DD)   // 2097152
#define NROW (BB * HH * SS)  // 32768 (bh*1024 + qrow)

typedef __attribute__((ext_vector_type(8))) short bf16x8;
typedef __attribute__((ext_vector_type(4))) short short4v;
typedef __attribute__((ext_vector_type(4))) float f32x4;

__device__ __forceinline__ short f2bf(float f) {
    union { float f; unsigned u; } v; v.f = f;
    unsigned r = v.u + 0x7FFFu + ((v.u >> 16) & 1u);   // RN-even
    return (short)(r >> 16);
}
__device__ __forceinline__ float bf2f(short s) {
    union { unsigned u; float f; } v;
    v.u = ((unsigned)(unsigned short)s) << 16;
    return v.f;
}

// ---------------------------------------------------------------------------
// x_bf = bf16(h[0] + h[1])
// ---------------------------------------------------------------------------
__global__ __launch_bounds__(256) void k_prep_x(const float* __restrict__ h,
                                                short* __restrict__ xbf) {
    int i = blockIdx.x * blockDim.x + threadIdx.x;
    const float4* h0 = (const float4*)h;
    const float4* h1 = (const float4*)(h + (size_t)BSD);
    float4 a0 = h0[2 * i], a1 = h0[2 * i + 1];
    float4 b0 = h1[2 * i], b1 = h1[2 * i + 1];
    bf16x8 o;
    o[0] = f2bf(a0.x + b0.x); o[1] = f2bf(a0.y + b0.y);
    o[2] = f2bf(a0.z + b0.z); o[3] = f2bf(a0.w + b0.w);
    o[4] = f2bf(a1.x + b1.x); o[5] = f2bf(a1.y + b1.y);
    o[6] = f2bf(a1.z + b1.z); o[7] = f2bf(a1.w + b1.w);
    ((bf16x8*)xbf)[i] = o;
}

__global__ __launch_bounds__(256) void k_prep_w(const float* __restrict__ wq,
                                                const float* __restrict__ wk,
                                                const float* __restrict__ wv,
                                                const float* __restrict__ wo,
                                                short* __restrict__ wbf) {
    int z = blockIdx.z;
    const float* src = (z == 0) ? wq : (z == 1) ? wk : (z == 2) ? wv : wo;
    short* dst = wbf + (size_t)z * (DD * DD);
    int i = blockIdx.x * blockDim.x + threadIdx.x;
    const float4* s4 = (const float4*)src;
    float4 a0 = s4[2 * i], a1 = s4[2 * i + 1];
    bf16x8 o;
    o[0] = f2bf(a0.x); o[1] = f2bf(a0.y); o[2] = f2bf(a0.z); o[3] = f2bf(a0.w);
    o[4] = f2bf(a1.x); o[5] = f2bf(a1.y); o[6] = f2bf(a1.z); o[7] = f2bf(a1.w);
    ((bf16x8*)dst)[i] = o;
}

// ---------------------------------------------------------------------------
// bf16 MFMA GEMM, 128x128 tile, BK=32. epi: 0 = f32 out (+bias),
// 1 = bf16 out [B,S,D] (+bias).
// ---------------------------------------------------------------------------
#define TM 128
#define TN 128
#define TK 32

__device__ __forceinline__ void gemm_bf16_body(const short* __restrict__ A,
                                               const short* __restrict__ W,
                                               const float* __restrict__ bias,
                                               float* __restrict__ Cf,
                                               short* __restrict__ Cb,
                                               int epi, int K, int N,
                                               int bm, int bn) {
    __shared__ __align__(16) short As[TM * TK];
    __shared__ __align__(16) short Bs[TN * TK];
    const int tid = threadIdx.x;
    const int lane = tid & 63;
    const int wid = tid >> 6;
    const int wm = wid >> 1;
    const int wn = wid & 1;
    const int lr = lane & 15;
    const int kq = lane >> 4;

    f32x4 acc[4][4];
#pragma unroll
    for (int i = 0; i < 4; ++i)
#pragma unroll
        for (int j = 0; j < 4; ++j) acc[i][j] = (f32x4)0.0f;

    for (int k0 = 0; k0 < K; k0 += TK) {
#pragma unroll
        for (int i = 0; i < 2; ++i) {
            int t = i * 256 + tid;
            int r = t >> 2;
            int kk = (t & 3) << 3;
            const short* ga = A + (size_t)(bm + r) * K + k0 + kk;
            __builtin_amdgcn_global_load_lds(
                (const __attribute__((address_space(1))) unsigned*)ga,
                (__attribute__((address_space(3))) unsigned*)&As[t * 8], 16, 0, 0);
            const short* gb = W + (size_t)(bn + r) * K + k0 + kk;
            __builtin_amdgcn_global_load_lds(
                (const __attribute__((address_space(1))) unsigned*)gb,
                (__attribute__((address_space(3))) unsigned*)&Bs[t * 8], 16, 0, 0);
        }
        __syncthreads();

        bf16x8 af[4], bfr[4];
#pragma unroll
        for (int f = 0; f < 4; ++f) {
            af[f]  = *(const bf16x8*)&As[(wm * 64 + f * 16 + lr) * TK + kq * 8];
            bfr[f] = *(const bf16x8*)&Bs[(wn * 64 + f * 16 + lr) * TK + kq * 8];
        }
#pragma unroll
        for (int fm = 0; fm < 4; ++fm)
#pragma unroll
            for (int fn = 0; fn < 4; ++fn)
                acc[fm][fn] = __builtin_amdgcn_mfma_f32_16x16x32_bf16(
                    af[fm], bfr[fn], acc[fm][fn], 0, 0, 0);
        __syncthreads();
    }

    // epilogue. C/D layout: col = lane&15, row = (lane>>4)*4 + reg.
#pragma unroll
    for (int fm = 0; fm < 4; ++fm) {
        int row0 = bm + wm * 64 + fm * 16 + kq * 4;
#pragma unroll
        for (int fn = 0; fn < 4; ++fn) {
            int col = bn + wn * 64 + fn * 16 + lr;
            float bv = bias[col];
            if (epi == 0) {
#pragma unroll
                for (int j = 0; j < 4; ++j)
                    Cf[(size_t)(row0 + j) * N + col] = acc[fm][fn][j] + bv;
            } else {
#pragma unroll
                for (int j = 0; j < 4; ++j)
                    Cb[(size_t)(row0 + j) * N + col] = f2bf(acc[fm][fn][j] + bv);
            }
        }
    }
}

__global__ __launch_bounds__(256) void k_gemm_qkv(
    const short* __restrict__ xbf, const short* __restrict__ wbf,
    const float* __restrict__ bq, const float* __restrict__ bk,
    const float* __restrict__ bv,
    short* __restrict__ qb, short* __restrict__ kb, short* __restrict__ vb) {
    int z = blockIdx.z;
    const short* W = wbf + (size_t)z * (DD * DD);
    const float* bias = (z == 0) ? bq : (z == 1) ? bk : bv;
    short* C = (z == 0) ? qb : (z == 1) ? kb : vb;
    gemm_bf16_body(xbf, W, bias, nullptr, C, 1, DD, DD,
                   blockIdx.y * TM, blockIdx.x * TN);
}

__global__ __launch_bounds__(256) void k_gemm_out(
    const short* __restrict__ A, const short* __restrict__ W,
    const float* __restrict__ bias, float* __restrict__ C) {
    gemm_bf16_body(A, W, bias, C, nullptr, 0, DD, DD,
                   blockIdx.y * TM, blockIdx.x * TN);
}

// ---------------------------------------------------------------------------
// V [B,S,D] (head slice) -> V^T [B*H][HDD][SS]  via LDS 64x64 tiles
// ---------------------------------------------------------------------------
__global__ __launch_bounds__(256) void k_transpose_v(const short* __restrict__ vb,
                                                     short* __restrict__ vt) {
    __shared__ short T[64][64 + 2];
    const int s0 = blockIdx.x << 6;
    const int bh = blockIdx.y;
    const int b = bh >> 4, h = bh & 15;
    const int tid = threadIdx.x;
    const short* src = vb + ((size_t)(b * SS + s0)) * DD + h * HDD;
#pragma unroll
    for (int i = 0; i < 2; ++i) {
        int t = i * 256 + tid;
        int s = t >> 3, dc = (t & 7) << 3;
        bf16x8 val = *(const bf16x8*)(src + (size_t)s * DD + dc);
#pragma unroll
        for (int e = 0; e < 8; ++e) T[s][dc + e] = val[e];
    }
    __syncthreads();
    short* dst = vt + (size_t)bh * HDD * SS + s0;   // [d][s]
#pragma unroll
    for (int i = 0; i < 2; ++i) {
        int t = i * 256 + tid;
        int d = t >> 3, sc = (t & 7) << 3;
        bf16x8 o;
#pragma unroll
        for (int e = 0; e < 8; ++e) o[e] = T[sc + e][d];
        *(bf16x8*)(dst + (size_t)d * SS + sc) = o;
    }
}

// ---------------------------------------------------------------------------
// MFMA flash attention, split-KV x2. grid (S/64, B*H, 2). 256 thr = 4 waves.
// R3-proven structure: K/V^T 64x64 bf16 tiles double-buffered in LDS via
// global_load_lds (linear dest + XOR-swizzled source), counted vmcnt(4),
// swizzled ds_read_b128. Partials (O bf16, m/l f32) merged by k_merge.
// ---------------------------------------------------------------------------
__global__ __launch_bounds__(256) void k_attn(
    const short* __restrict__ qb, const short* __restrict__ kb,
    const short* __restrict__ vt, const float* __restrict__ mask,
    short* __restrict__ Op, float* __restrict__ Mp, float* __restrict__ Lp) {
    __shared__ __align__(16) short Kls[2][64 * 64];
    __shared__ __align__(16) short Vls[2][64 * 64];
    __shared__ __align__(16) short Pls[4][16 * 64];

    const int bh = blockIdx.y;
    const int b = bh >> 4;
    const int h = bh & 15;
    const int q0 = blockIdx.x << 6;
    const int kvh = blockIdx.z;
    const int tbase = kvh << 9;          // 0 or 512
    const int tid = threadIdx.x;
    const int lane = tid & 63;
    const int w = tid >> 6;
    const int lr = lane & 15;
    const int kq = lane >> 4;
    const float scale = 0.125f;

    const short* khead = kb + (size_t)b * SS * DD + h * HDD;   // + kv*DD + d
    const short* vhead = vt + (size_t)bh * HDD * SS;           // + d*SS + kv
    const float* maskp = mask + b * SS;
    short* Pw = &Pls[w][0];

    bf16x8 qf[2];
    {
        const short* qrow = qb + ((size_t)(b * SS + q0 + w * 16 + lr)) * DD + h * HDD;
        qf[0] = *(const bf16x8*)(qrow + kq * 8);
        qf[1] = *(const bf16x8*)(qrow + 32 + kq * 8);
    }

    auto stage = [&](int t0, int bi) {
        const short* kbase = khead + (size_t)t0 * DD;
        const short* vbase = vhead + t0;
#pragma unroll
        for (int i = 0; i < 2; ++i) {
            int t = i * 256 + tid;
            int r = t >> 3;
            int cs = (t & 7) ^ (r & 7);
            __builtin_amdgcn_global_load_lds(
                (const __attribute__((address_space(1))) unsigned*)(kbase + (size_t)r * DD + cs * 8),
                (__attribute__((address_space(3))) unsigned*)&Kls[bi][t * 8], 16, 0, 0);
            __builtin_amdgcn_global_load_lds(
                (const __attribute__((address_space(1))) unsigned*)(vbase + (size_t)r * SS + cs * 8),
                (__attribute__((address_space(3))) unsigned*)&Vls[bi][t * 8], 16, 0, 0);
        }
    };

    float m_r[4], l_r[4];
    f32x4 O[4];
#pragma unroll
    for (int j = 0; j < 4; ++j) { m_r[j] = -3.0e38f; l_r[j] = 0.f; O[j] = (f32x4)0.0f; }

    auto body = [&](int t0, int cur) {
        const short* Kb = &Kls[cur][0];
        const short* Vb = &Vls[cur][0];

        // QK^T: S[q=kq*4+j][kv=fc*16+lr]
        bf16x8 kf[4][2];
#pragma unroll
        for (int fc = 0; fc < 4; ++fc) {
            int row = fc * 16 + lr;
            int sw = lr & 7;
            kf[fc][0] = *(const bf16x8*)&Kb[row * 64 + ((kq ^ sw) << 3)];
            kf[fc][1] = *(const bf16x8*)&Kb[row * 64 + (((4 + kq) ^ sw) << 3)];
        }
        f32x4 sacc[4];
#pragma unroll
        for (int fc = 0; fc < 4; ++fc) sacc[fc] = (f32x4)0.0f;
        __builtin_amdgcn_s_setprio(1);
#pragma unroll
        for (int fc = 0; fc < 4; ++fc) {
            sacc[fc] = __builtin_amdgcn_mfma_f32_16x16x32_bf16(qf[0], kf[fc][0], sacc[fc], 0, 0, 0);
            sacc[fc] = __builtin_amdgcn_mfma_f32_16x16x32_bf16(qf[1], kf[fc][1], sacc[fc], 0, 0, 0);
        }
        __builtin_amdgcn_s_setprio(0);

        float addv[4];
#pragma unroll
        for (int fc = 0; fc < 4; ++fc)
            addv[fc] = (1.0f - maskp[t0 + fc * 16 + lr]) * MASK_VAL;

        float s[4][4];
#pragma unroll
        for (int fc = 0; fc < 4; ++fc)
#pragma unroll
            for (int j = 0; j < 4; ++j)
                s[fc][j] = sacc[fc][j] * scale + addv[fc];

        // online softmax (defer-max: skip rescale when growth <= 8)
        float rm[4];
#pragma unroll
        for (int j = 0; j < 4; ++j) {
            rm[j] = fmaxf(fmaxf(s[0][j], s[1][j]), fmaxf(s[2][j], s[3][j]));
#pragma unroll
            for (int mo = 1; mo < 16; mo <<= 1)
                rm[j] = fmaxf(rm[j], __shfl_xor(rm[j], mo, 16));
        }
        bool sk = (rm[0] <= m_r[0] + 8.0f) && (rm[1] <= m_r[1] + 8.0f) &&
                  (rm[2] <= m_r[2] + 8.0f) && (rm[3] <= m_r[3] + 8.0f);
        if (!__all(sk)) {
#pragma unroll
            for (int j = 0; j < 4; ++j) {
                float mn = fmaxf(m_r[j], rm[j]);
                float alpha = __expf(m_r[j] - mn);
                m_r[j] = mn;
                l_r[j] *= alpha;
#pragma unroll
                for (int fd = 0; fd < 4; ++fd) O[fd][j] *= alpha;
            }
        }
        float rs[4];
#pragma unroll
        for (int j = 0; j < 4; ++j) rs[j] = 0.f;
#pragma unroll
        for (int fc = 0; fc < 4; ++fc)
#pragma unroll
            for (int j = 0; j < 4; ++j) {
                float p = __expf(s[fc][j] - m_r[j]);
                s[fc][j] = p;
                rs[j] += p;
            }
#pragma unroll
        for (int j = 0; j < 4; ++j) {
#pragma unroll
            for (int mo = 1; mo < 16; mo <<= 1)
                rs[j] += __shfl_xor(rs[j], mo, 16);
            l_r[j] += rs[j];
        }

        // P -> per-wave LDS (swizzled 128B rows), bf16
#pragma unroll
        for (int fc = 0; fc < 4; ++fc) {
            int col = fc * 16 + lr;
#pragma unroll
            for (int j = 0; j < 4; ++j) {
                int q = kq * 4 + j;
                Pw[q * 64 + ((((col >> 3) ^ (q & 7)) << 3) | (col & 7))] = f2bf(s[fc][j]);
            }
        }
        asm volatile("s_waitcnt lgkmcnt(0)" ::: "memory");

        // PV: O[q=kq*4+j][d=fd*16+lr] += P[q][kv] * V[kv][d]
        bf16x8 pa[2];
        {
            int sw = lr & 7;
            pa[0] = *(const bf16x8*)&Pw[lr * 64 + ((kq ^ sw) << 3)];
            pa[1] = *(const bf16x8*)&Pw[lr * 64 + (((4 + kq) ^ sw) << 3)];
        }
        __builtin_amdgcn_s_setprio(1);
#pragma unroll
        for (int fd = 0; fd < 4; ++fd) {
            int row = fd * 16 + lr;
            int sw = lr & 7;
            bf16x8 v0 = *(const bf16x8*)&Vb[row * 64 + ((kq ^ sw) << 3)];
            bf16x8 v1 = *(const bf16x8*)&Vb[row * 64 + (((4 + kq) ^ sw) << 3)];
            O[fd] = __builtin_amdgcn_mfma_f32_16x16x32_bf16(pa[0], v0, O[fd], 0, 0, 0);
            O[fd] = __builtin_amdgcn_mfma_f32_16x16x32_bf16(pa[1], v1, O[fd], 0, 0, 0);
        }
        __builtin_amdgcn_s_setprio(0);
    };

    stage(tbase, 0);
    for (int it = 0; it < 7; ++it) {
        stage(tbase + ((it + 1) << 6), (it + 1) & 1);
        asm volatile("s_waitcnt vmcnt(4)\n\ts_barrier" ::: "memory");
        body(tbase + (it << 6), it & 1);
        asm volatile("s_barrier" ::: "memory");
    }
    asm volatile("s_waitcnt vmcnt(0)\n\ts_barrier" ::: "memory");
    body(tbase + (7 << 6), 1);

    // write partials: O (bf16, un-normalized), m/l (f32, one lane per row)
    const int rowb = bh * SS + q0 + w * 16;
    short* ob = Op + ((size_t)kvh * NROW + rowb) * HDD;
#pragma unroll
    for (int j = 0; j < 4; ++j) {
        int qrow = kq * 4 + j;
#pragma unroll
        for (int fd = 0; fd < 4; ++fd)
            ob[(size_t)qrow * HDD + fd * 16 + lr] = f2bf(O[fd][j]);
        if (lr == 0) {
            Mp[kvh * NROW + rowb + qrow] = m_r[j];
            Lp[kvh * NROW + rowb + qrow] = l_r[j];
        }
    }
}

// ---------------------------------------------------------------------------
// merge split-KV partials -> ctx bf16 [B,S,D]
// ---------------------------------------------------------------------------
__global__ __launch_bounds__(256) void k_merge(
    const short* __restrict__ Op, const float* __restrict__ Mp,
    const float* __restrict__ Lp, short* __restrict__ ctx) {
    int idx = blockIdx.x * 256 + threadIdx.x;    // 0 .. NROW*16-1
    int row = idx >> 4;
    int d0 = (idx & 15) << 2;
    float m1 = Mp[row], m2 = Mp[NROW + row];
    float l1 = Lp[row], l2 = Lp[NROW + row];
    float m = fmaxf(m1, m2);
    float a1 = __expf(m1 - m), a2 = __expf(m2 - m);
    float inv = 1.0f / (l1 * a1 + l2 * a2);
    short4v o1 = *(const short4v*)&Op[(size_t)row * HDD + d0];
    short4v o2 = *(const short4v*)&Op[((size_t)NROW + row) * HDD + d0];
    int bh = row >> 10, qrow = row & 1023;
    int b = bh >> 4, h = bh & 15;
    short4v o;
    o.x = f2bf((bf2f(o1.x) * a1 + bf2f(o2.x) * a2) * inv);
    o.y = f2bf((bf2f(o1.y) * a1 + bf2f(o2.y) * a2) * inv);
    o.z = f2bf((bf2f(o1.z) * a1 + bf2f(o2.z) * a2) * inv);
    o.w = f2bf((bf2f(o1.w) * a1 + bf2f(o2.w) * a2) * inv);
    *(short4v*)&ctx[((size_t)(b * SS + qrow)) * DD + h * HDD + d0] = o;
}

// ---------------------------------------------------------------------------
extern "C" void kernel_launch(void* const* d_in, const int* in_sizes, int n_in,
                              void* d_out, int out_size, void* d_ws, size_t ws_size,
                              hipStream_t stream) {
    const float* h    = (const float*)d_in[0];
    const float* mask = (const float*)d_in[1];
    const float* wq   = (const float*)d_in[2];
    const float* bq   = (const float*)d_in[3];
    const float* wk   = (const float*)d_in[4];
    const float* bk   = (const float*)d_in[5];
    const float* wv   = (const float*)d_in[6];
    const float* bv   = (const float*)d_in[7];
    const float* wo   = (const float*)d_in[8];
    const float* bo   = (const float*)d_in[9];
    float* out = (float*)d_out;

    char* base = (char*)d_ws;
    short* x_bf  = (short*)base;                       // 4 MB @ 0
    short* w_bf  = (short*)(base + (4u << 20));        // 8 MB @ 4
    short* q_bf  = (short*)(base + (12u << 20));       // 4 MB @ 12
    short* k_bf  = (short*)(base + (16u << 20));       // 4 MB @ 16
    short* v_bf  = (short*)(base + (20u << 20));       // 4 MB @ 20
    short* v_t   = (short*)(base + (24u << 20));       // 4 MB @ 24
    short* ctxbf = (short*)(base + (28u << 20));       // 4 MB @ 28
    short* Op    = (short*)(base + (32u << 20));       // 8 MB @ 32 (2x NROW x 64 bf16)
    float* Mp    = (float*)(base + (40u << 20));       // 256 KB
    float* Lp    = (float*)(base + (40u << 20) + (NROW * 2 * sizeof(float)));

    k_prep_x<<<BSD / 8 / 256, 256, 0, stream>>>(h, x_bf);
    k_prep_w<<<dim3(DD * DD / 8 / 256, 1, 4), 256, 0, stream>>>(wq, wk, wv, wo, w_bf);

    dim3 gqkv(DD / TN, BB * SS / TM, 3);
    k_gemm_qkv<<<gqkv, 256, 0, stream>>>(x_bf, w_bf, bq, bk, bv, q_bf, k_bf, v_bf);

    dim3 gtr(SS / 64, BB * HH);
    k_transpose_v<<<gtr, 256, 0, stream>>>(v_bf, v_t);

    dim3 gattn(SS / 64, BB * HH, 2);
    k_attn<<<gattn, 256, 0, stream>>>(q_bf, k_bf, v_t, mask, Op, Mp, Lp);

    k_merge<<<NROW * 16 / 256, 256, 0, stream>>>(Op, Mp, Lp, ctxbf);

    dim3 gout(DD / TN, BB * SS / TM);
    k_gemm_out<<<gout, 256, 0, stream>>>(ctxbf, w_bf + (size_t)3 * DD * DD, bo, out);
}

// Round 6
// 88.382 us; speedup vs baseline: 1.3850x; 1.1608x over previous
//
#include <hip/hip_runtime.h>
#include <hip/hip_bf16.h>

#define BB 2
#define SS 1024
#define DD 1024
#define HH 16
#define HDD 64
#define MASK_VAL -10000.0f
#define BSD (BB * SS * DD)   // 2097152
#define NROW (BB * HH * SS)  // 32768 (bh*1024 + qrow)

typedef __attribute__((ext_vector_type(8))) short bf16x8;
typedef __attribute__((ext_vector_type(4))) short short4v;
typedef __attribute__((ext_vector_type(4))) float f32x4;
typedef __attribute__((ext_vector_type(16))) float f32x16;
typedef __attribute__((ext_vector_type(4))) unsigned int uint4v;

__device__ __forceinline__ short f2bf(float f) {
    union { float f; unsigned u; } v; v.f = f;
    unsigned r = v.u + 0x7FFFu + ((v.u >> 16) & 1u);   // RN-even
    return (short)(r >> 16);
}
__device__ __forceinline__ float bf2f(short s) {
    union { unsigned u; float f; } v;
    v.u = ((unsigned)(unsigned short)s) << 16;
    return v.f;
}
__device__ __forceinline__ unsigned cvt_pk_bf16(float lo, float hi) {
    unsigned r;
    asm("v_cvt_pk_bf16_f32 %0, %1, %2" : "=v"(r) : "v"(lo), "v"(hi));
    return r;
}
// a' = [a_lo | b_lo], b' = [a_hi | b_hi]  (halves = lane<32 vs lane>=32)
__device__ __forceinline__ void plane32_swap(unsigned& a, unsigned& b) {
#if __has_builtin(__builtin_amdgcn_permlane32_swap)
    auto r = __builtin_amdgcn_permlane32_swap(a, b, false, false);
    a = r[0]; b = r[1];
#else
    unsigned as = (unsigned)__shfl_xor((int)a, 32);
    unsigned bs = (unsigned)__shfl_xor((int)b, 32);
    bool lo = ((threadIdx.x & 63) < 32);
    unsigned na = lo ? a : bs;
    unsigned nb = lo ? as : b;
    a = na; b = nb;
#endif
}

// ---------------------------------------------------------------------------
// x_bf = bf16(h[0] + h[1])
// ---------------------------------------------------------------------------
__global__ __launch_bounds__(256) void k_prep_x(const float* __restrict__ h,
                                                short* __restrict__ xbf) {
    int i = blockIdx.x * blockDim.x + threadIdx.x;
    const float4* h0 = (const float4*)h;
    const float4* h1 = (const float4*)(h + (size_t)BSD);
    float4 a0 = h0[2 * i], a1 = h0[2 * i + 1];
    float4 b0 = h1[2 * i], b1 = h1[2 * i + 1];
    bf16x8 o;
    o[0] = f2bf(a0.x + b0.x); o[1] = f2bf(a0.y + b0.y);
    o[2] = f2bf(a0.z + b0.z); o[3] = f2bf(a0.w + b0.w);
    o[4] = f2bf(a1.x + b1.x); o[5] = f2bf(a1.y + b1.y);
    o[6] = f2bf(a1.z + b1.z); o[7] = f2bf(a1.w + b1.w);
    ((bf16x8*)xbf)[i] = o;
}

__global__ __launch_bounds__(256) void k_prep_w(const float* __restrict__ wq,
                                                const float* __restrict__ wk,
                                                const float* __restrict__ wv,
                                                const float* __restrict__ wo,
                                                short* __restrict__ wbf) {
    int z = blockIdx.z;
    const float* src = (z == 0) ? wq : (z == 1) ? wk : (z == 2) ? wv : wo;
    short* dst = wbf + (size_t)z * (DD * DD);
    int i = blockIdx.x * blockDim.x + threadIdx.x;
    const float4* s4 = (const float4*)src;
    float4 a0 = s4[2 * i], a1 = s4[2 * i + 1];
    bf16x8 o;
    o[0] = f2bf(a0.x); o[1] = f2bf(a0.y); o[2] = f2bf(a0.z); o[3] = f2bf(a0.w);
    o[4] = f2bf(a1.x); o[5] = f2bf(a1.y); o[6] = f2bf(a1.z); o[7] = f2bf(a1.w);
    ((bf16x8*)dst)[i] = o;
}

// ---------------------------------------------------------------------------
// bf16 MFMA GEMM, 128x128 tile, BK=32. epi: 0 = f32 out (+bias),
// 1 = bf16 out [B,S,D] (+bias).
// ---------------------------------------------------------------------------
#define TM 128
#define TN 128
#define TK 32

__device__ __forceinline__ void gemm_bf16_body(const short* __restrict__ A,
                                               const short* __restrict__ W,
                                               const float* __restrict__ bias,
                                               float* __restrict__ Cf,
                                               short* __restrict__ Cb,
                                               int epi, int K, int N,
                                               int bm, int bn) {
    __shared__ __align__(16) short As[TM * TK];
    __shared__ __align__(16) short Bs[TN * TK];
    const int tid = threadIdx.x;
    const int lane = tid & 63;
    const int wid = tid >> 6;
    const int wm = wid >> 1;
    const int wn = wid & 1;
    const int lr = lane & 15;
    const int kq = lane >> 4;

    f32x4 acc[4][4];
#pragma unroll
    for (int i = 0; i < 4; ++i)
#pragma unroll
        for (int j = 0; j < 4; ++j) acc[i][j] = (f32x4)0.0f;

    for (int k0 = 0; k0 < K; k0 += TK) {
#pragma unroll
        for (int i = 0; i < 2; ++i) {
            int t = i * 256 + tid;
            int r = t >> 2;
            int kk = (t & 3) << 3;
            const short* ga = A + (size_t)(bm + r) * K + k0 + kk;
            __builtin_amdgcn_global_load_lds(
                (const __attribute__((address_space(1))) unsigned*)ga,
                (__attribute__((address_space(3))) unsigned*)&As[t * 8], 16, 0, 0);
            const short* gb = W + (size_t)(bn + r) * K + k0 + kk;
            __builtin_amdgcn_global_load_lds(
                (const __attribute__((address_space(1))) unsigned*)gb,
                (__attribute__((address_space(3))) unsigned*)&Bs[t * 8], 16, 0, 0);
        }
        __syncthreads();

        bf16x8 af[4], bfr[4];
#pragma unroll
        for (int f = 0; f < 4; ++f) {
            af[f]  = *(const bf16x8*)&As[(wm * 64 + f * 16 + lr) * TK + kq * 8];
            bfr[f] = *(const bf16x8*)&Bs[(wn * 64 + f * 16 + lr) * TK + kq * 8];
        }
#pragma unroll
        for (int fm = 0; fm < 4; ++fm)
#pragma unroll
            for (int fn = 0; fn < 4; ++fn)
                acc[fm][fn] = __builtin_amdgcn_mfma_f32_16x16x32_bf16(
                    af[fm], bfr[fn], acc[fm][fn], 0, 0, 0);
        __syncthreads();
    }

    // epilogue. C/D layout: col = lane&15, row = (lane>>4)*4 + reg.
#pragma unroll
    for (int fm = 0; fm < 4; ++fm) {
        int row0 = bm + wm * 64 + fm * 16 + kq * 4;
#pragma unroll
        for (int fn = 0; fn < 4; ++fn) {
            int col = bn + wn * 64 + fn * 16 + lr;
            float bv = bias[col];
            if (epi == 0) {
#pragma unroll
                for (int j = 0; j < 4; ++j)
                    Cf[(size_t)(row0 + j) * N + col] = acc[fm][fn][j] + bv;
            } else {
#pragma unroll
                for (int j = 0; j < 4; ++j)
                    Cb[(size_t)(row0 + j) * N + col] = f2bf(acc[fm][fn][j] + bv);
            }
        }
    }
}

__global__ __launch_bounds__(256) void k_gemm_qkv(
    const short* __restrict__ xbf, const short* __restrict__ wbf,
    const float* __restrict__ bq, const float* __restrict__ bk,
    const float* __restrict__ bv,
    short* __restrict__ qb, short* __restrict__ kb, short* __restrict__ vb) {
    int z = blockIdx.z;
    const short* W = wbf + (size_t)z * (DD * DD);
    const float* bias = (z == 0) ? bq : (z == 1) ? bk : bv;
    short* C = (z == 0) ? qb : (z == 1) ? kb : vb;
    gemm_bf16_body(xbf, W, bias, nullptr, C, 1, DD, DD,
                   blockIdx.y * TM, blockIdx.x * TN);
}

__global__ __launch_bounds__(256) void k_gemm_out(
    const short* __restrict__ A, const short* __restrict__ W,
    const float* __restrict__ bias, float* __restrict__ C) {
    gemm_bf16_body(A, W, bias, C, nullptr, 0, DD, DD,
                   blockIdx.y * TM, blockIdx.x * TN);
}

// ---------------------------------------------------------------------------
// V [B,S,D] (head slice) -> V^T [B*H][HDD][SS]  via LDS 64x64 tiles
// ---------------------------------------------------------------------------
__global__ __launch_bounds__(256) void k_transpose_v(const short* __restrict__ vb,
                                                     short* __restrict__ vt) {
    __shared__ short T[64][64 + 2];
    const int s0 = blockIdx.x << 6;
    const int bh = blockIdx.y;
    const int b = bh >> 4, h = bh & 15;
    const int tid = threadIdx.x;
    const short* src = vb + ((size_t)(b * SS + s0)) * DD + h * HDD;
#pragma unroll
    for (int i = 0; i < 2; ++i) {
        int t = i * 256 + tid;
        int s = t >> 3, dc = (t & 7) << 3;
        bf16x8 val = *(const bf16x8*)(src + (size_t)s * DD + dc);
#pragma unroll
        for (int e = 0; e < 8; ++e) T[s][dc + e] = val[e];
    }
    __syncthreads();
    short* dst = vt + (size_t)bh * HDD * SS + s0;   // [d][s]
#pragma unroll
    for (int i = 0; i < 2; ++i) {
        int t = i * 256 + tid;
        int d = t >> 3, sc = (t & 7) << 3;
        bf16x8 o;
#pragma unroll
        for (int e = 0; e < 8; ++e) o[e] = T[sc + e][d];
        *(bf16x8*)(dst + (size_t)d * SS + sc) = o;
    }
}

// ---------------------------------------------------------------------------
// MFMA flash attention, swapped-QK^T 32x32 design, split-KV x2.
// grid (S/128, B*H, 2), 256 thr = 4 waves x 32 q-rows.
// S^T = mfma(K, Q): lane owns q = lane&31; softmax fully in-register
// (fmax/add tree + one shfl_xor(32)). P -> PV A-frag via cvt_pk_bf16 +
// permlane32_swap (no LDS round-trip). K/V^T staged dbuf via
// global_load_lds + XOR source swizzle, counted vmcnt(4).
// ---------------------------------------------------------------------------
__global__ __launch_bounds__(256) void k_attn(
    const short* __restrict__ qb, const short* __restrict__ kb,
    const short* __restrict__ vt, const float* __restrict__ mask,
    short* __restrict__ Op, float* __restrict__ Mp, float* __restrict__ Lp) {
    __shared__ __align__(16) short Kls[2][64 * 64];
    __shared__ __align__(16) short Vls[2][64 * 64];

    const int bh = blockIdx.y;
    const int b = bh >> 4;
    const int h = bh & 15;
    const int q0 = blockIdx.x << 7;      // 128 q-rows per block
    const int kvh = blockIdx.z;
    const int tbase = kvh << 9;          // 0 or 512
    const int tid = threadIdx.x;
    const int lane = tid & 63;
    const int w = tid >> 6;
    const int ql = lane & 31;            // q within wave tile; also d-lane for O
    const int hi = lane >> 5;
    const int rsw = ql & 7;              // LDS chunk swizzle key
    const float scale = 0.125f;

    const short* khead = kb + (size_t)b * SS * DD + h * HDD;   // + kv*DD + d
    const short* vhead = vt + (size_t)bh * HDD * SS;           // + d*SS + kv
    const float* maskp = mask + b * SS;

    // Q B-fragments: lane supplies col q=ql, k-slice d = step*16 + hi*8 + e
    bf16x8 qf0, qf1, qf2, qf3;
    {
        const short* qrow = qb + ((size_t)(b * SS + q0 + w * 32 + ql)) * DD + h * HDD + hi * 8;
        qf0 = *(const bf16x8*)(qrow);
        qf1 = *(const bf16x8*)(qrow + 16);
        qf2 = *(const bf16x8*)(qrow + 32);
        qf3 = *(const bf16x8*)(qrow + 48);
    }

    auto stage = [&](int t0, int bi) {
        const short* kbase = khead + (size_t)t0 * DD;
        const short* vbase = vhead + t0;
#pragma unroll
        for (int i = 0; i < 2; ++i) {
            int t = i * 256 + tid;
            int r = t >> 3;
            int cs = (t & 7) ^ (r & 7);
            __builtin_amdgcn_global_load_lds(
                (const __attribute__((address_space(1))) unsigned*)(kbase + (size_t)r * DD + cs * 8),
                (__attribute__((address_space(3))) unsigned*)&Kls[bi][t * 8], 16, 0, 0);
            __builtin_amdgcn_global_load_lds(
                (const __attribute__((address_space(1))) unsigned*)(vbase + (size_t)r * SS + cs * 8),
                (__attribute__((address_space(3))) unsigned*)&Vls[bi][t * 8], 16, 0, 0);
        }
    };

    float m_r = -3.0e38f, l_r = 0.0f;
    f32x16 O0 = (f32x16)0.0f, O1 = (f32x16)0.0f;   // d-halves 0..31 / 32..63

    auto body = [&](int t0, int cur) {
        const short* Kb = &Kls[cur][0];
        const short* Vb = &Vls[cur][0];

        // ---- QK^T (swapped): s0 = S^T[kv 0..31][q], s1 = S^T[kv 32..63][q]
        f32x16 s0 = (f32x16)0.0f, s1 = (f32x16)0.0f;
        __builtin_amdgcn_s_setprio(1);
#pragma unroll
        for (int step = 0; step < 4; ++step) {
            int cpos = ((step << 1) | hi) ^ rsw;
            bf16x8 k0 = *(const bf16x8*)&Kb[ql * 64 + (cpos << 3)];
            bf16x8 k1 = *(const bf16x8*)&Kb[(32 + ql) * 64 + (cpos << 3)];
            bf16x8 qf = (step == 0) ? qf0 : (step == 1) ? qf1 : (step == 2) ? qf2 : qf3;
            s0 = __builtin_amdgcn_mfma_f32_32x32x16_bf16(k0, qf, s0, 0, 0, 0);
            s1 = __builtin_amdgcn_mfma_f32_32x32x16_bf16(k1, qf, s1, 0, 0, 0);
        }
        __builtin_amdgcn_s_setprio(0);

        // ---- scale + additive mask; reg r -> kv = (r&3) + 8*(r>>2) + 4*hi
#pragma unroll
        for (int g = 0; g < 4; ++g) {
            float4 a4 = *(const float4*)&maskp[t0 + 8 * g + 4 * hi];
            float4 b4 = *(const float4*)&maskp[t0 + 32 + 8 * g + 4 * hi];
            s0[4 * g + 0] = fmaf(s0[4 * g + 0], scale, (1.0f - a4.x) * MASK_VAL);
            s0[4 * g + 1] = fmaf(s0[4 * g + 1], scale, (1.0f - a4.y) * MASK_VAL);
            s0[4 * g + 2] = fmaf(s0[4 * g + 2], scale, (1.0f - a4.z) * MASK_VAL);
            s0[4 * g + 3] = fmaf(s0[4 * g + 3], scale, (1.0f - a4.w) * MASK_VAL);
            s1[4 * g + 0] = fmaf(s1[4 * g + 0], scale, (1.0f - b4.x) * MASK_VAL);
            s1[4 * g + 1] = fmaf(s1[4 * g + 1], scale, (1.0f - b4.y) * MASK_VAL);
            s1[4 * g + 2] = fmaf(s1[4 * g + 2], scale, (1.0f - b4.z) * MASK_VAL);
            s1[4 * g + 3] = fmaf(s1[4 * g + 3], scale, (1.0f - b4.w) * MASK_VAL);
        }

        // ---- in-register row max (tree) + half-exchange
        float mt[16];
#pragma unroll
        for (int r = 0; r < 16; ++r) mt[r] = fmaxf(s0[r], s1[r]);
#pragma unroll
        for (int st = 8; st > 0; st >>= 1)
#pragma unroll
            for (int r = 0; r < 8; ++r)
                if (r < st) mt[r] = fmaxf(mt[r], mt[r + st]);
        float mx = fmaxf(mt[0], __shfl_xor(mt[0], 32));

        // defer-max: rescale only if some row grew past threshold
        bool need = mx > m_r + 8.0f;
        if (__any(need)) {
            float mn = fmaxf(m_r, mx);
            float alpha = __expf(m_r - mn);
            m_r = mn;
            l_r *= alpha;
#pragma unroll
            for (int r = 0; r < 16; ++r) {
                int qrow = (r & 3) + 8 * (r >> 2) + 4 * hi;
                float al = __shfl(alpha, qrow, 64);
                O0[r] *= al;
                O1[r] *= al;
            }
        }

        // ---- p = exp(s - m), row sum (tree) + half-exchange
        float st0[16];
#pragma unroll
        for (int r = 0; r < 16; ++r) {
            s0[r] = __expf(s0[r] - m_r);
            s1[r] = __expf(s1[r] - m_r);
            st0[r] = s0[r] + s1[r];
        }
#pragma unroll
        for (int st = 8; st > 0; st >>= 1)
#pragma unroll
            for (int r = 0; r < 8; ++r)
                if (r < st) st0[r] += st0[r + st];
        l_r += st0[0] + __shfl_xor(st0[0], 32);

        // ---- pack P to bf16 + permlane32_swap -> PV A-fragments ----
        // subtile 0 (kv 0..31)
        unsigned w0 = cvt_pk_bf16(s0[0], s0[1]),  w1 = cvt_pk_bf16(s0[2], s0[3]);
        unsigned w2 = cvt_pk_bf16(s0[4], s0[5]),  w3 = cvt_pk_bf16(s0[6], s0[7]);
        unsigned w4 = cvt_pk_bf16(s0[8], s0[9]),  w5 = cvt_pk_bf16(s0[10], s0[11]);
        unsigned w6 = cvt_pk_bf16(s0[12], s0[13]), w7 = cvt_pk_bf16(s0[14], s0[15]);
        plane32_swap(w0, w2); plane32_swap(w1, w3);
        plane32_swap(w4, w6); plane32_swap(w5, w7);
        uint4v f0 = {w0, w1, w2, w3};   // kv 0..15
        uint4v f1 = {w4, w5, w6, w7};   // kv 16..31
        // subtile 1 (kv 32..63)
        unsigned x0 = cvt_pk_bf16(s1[0], s1[1]),  x1 = cvt_pk_bf16(s1[2], s1[3]);
        unsigned x2 = cvt_pk_bf16(s1[4], s1[5]),  x3 = cvt_pk_bf16(s1[6], s1[7]);
        unsigned x4 = cvt_pk_bf16(s1[8], s1[9]),  x5 = cvt_pk_bf16(s1[10], s1[11]);
        unsigned x6 = cvt_pk_bf16(s1[12], s1[13]), x7 = cvt_pk_bf16(s1[14], s1[15]);
        plane32_swap(x0, x2); plane32_swap(x1, x3);
        plane32_swap(x4, x6); plane32_swap(x5, x7);
        uint4v f2 = {x0, x1, x2, x3};   // kv 32..47
        uint4v f3 = {x4, x5, x6, x7};   // kv 48..63

        bf16x8 pf0 = __builtin_bit_cast(bf16x8, f0);
        bf16x8 pf1 = __builtin_bit_cast(bf16x8, f1);
        bf16x8 pf2 = __builtin_bit_cast(bf16x8, f2);
        bf16x8 pf3 = __builtin_bit_cast(bf16x8, f3);

        // ---- PV: O[q][d] += P[q][kv] * V[kv][d]; B-frag from V^T LDS ----
        __builtin_amdgcn_s_setprio(1);
#pragma unroll
        for (int ks = 0; ks < 4; ++ks) {
            int cpos = ((ks << 1) | hi) ^ rsw;
            bf16x8 pf = (ks == 0) ? pf0 : (ks == 1) ? pf1 : (ks == 2) ? pf2 : pf3;
            bf16x8 v0 = *(const bf16x8*)&Vb[ql * 64 + (cpos << 3)];
            bf16x8 v1 = *(const bf16x8*)&Vb[(32 + ql) * 64 + (cpos << 3)];
            O0 = __builtin_amdgcn_mfma_f32_32x32x16_bf16(pf, v0, O0, 0, 0, 0);
            O1 = __builtin_amdgcn_mfma_f32_32x32x16_bf16(pf, v1, O1, 0, 0, 0);
        }
        __builtin_amdgcn_s_setprio(0);
    };

    stage(tbase, 0);
    for (int it = 0; it < 7; ++it) {
        stage(tbase + ((it + 1) << 6), (it + 1) & 1);
        asm volatile("s_waitcnt vmcnt(4)\n\ts_barrier" ::: "memory");
        body(tbase + (it << 6), it & 1);
        asm volatile("s_barrier" ::: "memory");
    }
    asm volatile("s_waitcnt vmcnt(0)\n\ts_barrier" ::: "memory");
    body(tbase + (7 << 6), 1);

    // ---- write partials: O (bf16, un-normalized), m/l per q-row ----
    const int rowb = bh * SS + q0 + w * 32;
    short* ob = Op + ((size_t)kvh * NROW + rowb) * HDD;
#pragma unroll
    for (int r = 0; r < 16; ++r) {
        int qrow = (r & 3) + 8 * (r >> 2) + 4 * hi;
        ob[(size_t)qrow * HDD + ql] = f2bf(O0[r]);
        ob[(size_t)qrow * HDD + 32 + ql] = f2bf(O1[r]);
    }
    if (lane < 32) {
        Mp[kvh * NROW + rowb + lane] = m_r;
        Lp[kvh * NROW + rowb + lane] = l_r;
    }
}

// ---------------------------------------------------------------------------
// merge split-KV partials -> ctx bf16 [B,S,D]
// ---------------------------------------------------------------------------
__global__ __launch_bounds__(256) void k_merge(
    const short* __restrict__ Op, const float* __restrict__ Mp,
    const float* __restrict__ Lp, short* __restrict__ ctx) {
    int idx = blockIdx.x * 256 + threadIdx.x;    // 0 .. NROW*16-1
    int row = idx >> 4;
    int d0 = (idx & 15) << 2;
    float m1 = Mp[row], m2 = Mp[NROW + row];
    float l1 = Lp[row], l2 = Lp[NROW + row];
    float m = fmaxf(m1, m2);
    float a1 = __expf(m1 - m), a2 = __expf(m2 - m);
    float inv = 1.0f / (l1 * a1 + l2 * a2);
    short4v o1 = *(const short4v*)&Op[(size_t)row * HDD + d0];
    short4v o2 = *(const short4v*)&Op[((size_t)NROW + row) * HDD + d0];
    int bh = row >> 10, qrow = row & 1023;
    int b = bh >> 4, h = bh & 15;
    short4v o;
    o.x = f2bf((bf2f(o1.x) * a1 + bf2f(o2.x) * a2) * inv);
    o.y = f2bf((bf2f(o1.y) * a1 + bf2f(o2.y) * a2) * inv);
    o.z = f2bf((bf2f(o1.z) * a1 + bf2f(o2.z) * a2) * inv);
    o.w = f2bf((bf2f(o1.w) * a1 + bf2f(o2.w) * a2) * inv);
    *(short4v*)&ctx[((size_t)(b * SS + qrow)) * DD + h * HDD + d0] = o;
}

// ---------------------------------------------------------------------------
extern "C" void kernel_launch(void* const* d_in, const int* in_sizes, int n_in,
                              void* d_out, int out_size, void* d_ws, size_t ws_size,
                              hipStream_t stream) {
    const float* h    = (const float*)d_in[0];
    const float* mask = (const float*)d_in[1];
    const float* wq   = (const float*)d_in[2];
    const float* bq   = (const float*)d_in[3];
    const float* wk   = (const float*)d_in[4];
    const float* bk   = (const float*)d_in[5];
    const float* wv   = (const float*)d_in[6];
    const float* bv   = (const float*)d_in[7];
    const float* wo   = (const float*)d_in[8];
    const float* bo   = (const float*)d_in[9];
    float* out = (float*)d_out;

    char* base = (char*)d_ws;
    short* x_bf  = (short*)base;                       // 4 MB @ 0
    short* w_bf  = (short*)(base + (4u << 20));        // 8 MB @ 4
    short* q_bf  = (short*)(base + (12u << 20));       // 4 MB @ 12
    short* k_bf  = (short*)(base + (16u << 20));       // 4 MB @ 16
    short* v_bf  = (short*)(base + (20u << 20));       // 4 MB @ 20
    short* v_t   = (short*)(base + (24u << 20));       // 4 MB @ 24
    short* ctxbf = (short*)(base + (28u << 20));       // 4 MB @ 28
    short* Op    = (short*)(base + (32u << 20));       // 8 MB @ 32
    float* Mp    = (float*)(base + (40u << 20));       // 256 KB
    float* Lp    = (float*)(base + (40u << 20) + (NROW * 2 * sizeof(float)));

    k_prep_x<<<BSD / 8 / 256, 256, 0, stream>>>(h, x_bf);
    k_prep_w<<<dim3(DD * DD / 8 / 256, 1, 4), 256, 0, stream>>>(wq, wk, wv, wo, w_bf);

    dim3 gqkv(DD / TN, BB * SS / TM, 3);
    k_gemm_qkv<<<gqkv, 256, 0, stream>>>(x_bf, w_bf, bq, bk, bv, q_bf, k_bf, v_bf);

    dim3 gtr(SS / 64, BB * HH);
    k_transpose_v<<<gtr, 256, 0, stream>>>(v_bf, v_t);

    dim3 gattn(SS / 128, BB * HH, 2);
    k_attn<<<gattn, 256, 0, stream>>>(q_bf, k_bf, v_t, mask, Op, Mp, Lp);

    k_merge<<<NROW * 16 / 256, 256, 0, stream>>>(Op, Mp, Lp, ctxbf);

    dim3 gout(DD / TN, BB * SS / TM);
    k_gemm_out<<<gout, 256, 0, stream>>>(ctxbf, w_bf + (size_t)3 * DD * DD, bo, out);
}

// Round 7
// 85.600 us; speedup vs baseline: 1.4300x; 1.0325x over previous
//
#include <hip/hip_runtime.h>
#include <hip/hip_bf16.h>

#define BB 2
#define SS 1024
#define DD 1024
#define HH 16
#define HDD 64
#define MASK_VAL -10000.0f
#define BSD (BB * SS * DD)   // 2097152
#define NROW (BB * HH * SS)  // 32768 (bh*1024 + qrow)

typedef __attribute__((ext_vector_type(8))) short bf16x8;
typedef __attribute__((ext_vector_type(4))) short short4v;
typedef __attribute__((ext_vector_type(4))) float f32x4;
typedef __attribute__((ext_vector_type(16))) float f32x16;
typedef __attribute__((ext_vector_type(4))) unsigned int uint4v;

__device__ __forceinline__ short f2bf(float f) {
    union { float f; unsigned u; } v; v.f = f;
    unsigned r = v.u + 0x7FFFu + ((v.u >> 16) & 1u);   // RN-even
    return (short)(r >> 16);
}
__device__ __forceinline__ float bf2f(short s) {
    union { unsigned u; float f; } v;
    v.u = ((unsigned)(unsigned short)s) << 16;
    return v.f;
}
__device__ __forceinline__ unsigned cvt_pk_bf16(float lo, float hi) {
    unsigned r;
    asm("v_cvt_pk_bf16_f32 %0, %1, %2" : "=v"(r) : "v"(lo), "v"(hi));
    return r;
}
__device__ __forceinline__ void plane32_swap(unsigned& a, unsigned& b) {
#if __has_builtin(__builtin_amdgcn_permlane32_swap)
    auto r = __builtin_amdgcn_permlane32_swap(a, b, false, false);
    a = r[0]; b = r[1];
#else
    unsigned as = (unsigned)__shfl_xor((int)a, 32);
    unsigned bs = (unsigned)__shfl_xor((int)b, 32);
    bool lo = ((threadIdx.x & 63) < 32);
    unsigned na = lo ? a : bs;
    unsigned nb = lo ? as : b;
    a = na; b = nb;
#endif
}

// ---------------------------------------------------------------------------
// fused prep: z=0 -> x_bf = bf16(h0+h1); z=1..4 -> weight z-1 to bf16
// ---------------------------------------------------------------------------
__global__ __launch_bounds__(256) void k_prep(
    const float* __restrict__ h,
    const float* __restrict__ wq, const float* __restrict__ wk,
    const float* __restrict__ wv, const float* __restrict__ wo,
    short* __restrict__ xbf, short* __restrict__ wbf) {
    int z = blockIdx.z;
    int i = blockIdx.x * 256 + threadIdx.x;
    if (z == 0) {
        const float4* h0 = (const float4*)h;
        const float4* h1 = (const float4*)(h + (size_t)BSD);
        float4 a0 = h0[2 * i], a1 = h0[2 * i + 1];
        float4 b0 = h1[2 * i], b1 = h1[2 * i + 1];
        bf16x8 o;
        o[0] = f2bf(a0.x + b0.x); o[1] = f2bf(a0.y + b0.y);
        o[2] = f2bf(a0.z + b0.z); o[3] = f2bf(a0.w + b0.w);
        o[4] = f2bf(a1.x + b1.x); o[5] = f2bf(a1.y + b1.y);
        o[6] = f2bf(a1.z + b1.z); o[7] = f2bf(a1.w + b1.w);
        ((bf16x8*)xbf)[i] = o;
    } else {
        if (blockIdx.x >= 512) return;
        const float* src = (z == 1) ? wq : (z == 2) ? wk : (z == 3) ? wv : wo;
        short* dst = wbf + (size_t)(z - 1) * (DD * DD);
        const float4* s4 = (const float4*)src;
        float4 a0 = s4[2 * i], a1 = s4[2 * i + 1];
        bf16x8 o;
        o[0] = f2bf(a0.x); o[1] = f2bf(a0.y); o[2] = f2bf(a0.z); o[3] = f2bf(a0.w);
        o[4] = f2bf(a1.x); o[5] = f2bf(a1.y); o[6] = f2bf(a1.z); o[7] = f2bf(a1.w);
        ((bf16x8*)dst)[i] = o;
    }
}

// ---------------------------------------------------------------------------
// QKV bf16 MFMA GEMM, 128x128 tile, BK=32, 512 threads (8 waves, 2Mx4N,
// each wave 64x32 = 4x2 frags of 16x16x32). bf16 out [B,S,D] + bias.
// ---------------------------------------------------------------------------
#define TM 128
#define TN 128
#define TK 32

__global__ __launch_bounds__(512) void k_gemm_qkv(
    const short* __restrict__ xbf, const short* __restrict__ wbf,
    const float* __restrict__ bq, const float* __restrict__ bk,
    const float* __restrict__ bv,
    short* __restrict__ qb, short* __restrict__ kb, short* __restrict__ vb) {
    __shared__ __align__(16) short As[TM * TK];
    __shared__ __align__(16) short Bs[TN * TK];
    const int z = blockIdx.z;
    const short* A = xbf;
    const short* W = wbf + (size_t)z * (DD * DD);
    const float* bias = (z == 0) ? bq : (z == 1) ? bk : bv;
    short* C = (z == 0) ? qb : (z == 1) ? kb : vb;
    const int bm = blockIdx.y * TM;
    const int bn = blockIdx.x * TN;
    const int tid = threadIdx.x;
    const int lane = tid & 63;
    const int wid = tid >> 6;         // 0..7
    const int wm = wid & 1;           // M 64-half
    const int wn = wid >> 1;          // N 32-quarter
    const int lr = lane & 15;
    const int kq = lane >> 4;

    f32x4 acc[4][2];
#pragma unroll
    for (int i = 0; i < 4; ++i)
#pragma unroll
        for (int j = 0; j < 2; ++j) acc[i][j] = (f32x4)0.0f;

    const int sr = tid >> 2;          // 0..127
    const int sk = (tid & 3) << 3;    // 0,8,16,24

    for (int k0 = 0; k0 < DD; k0 += TK) {
        __builtin_amdgcn_global_load_lds(
            (const __attribute__((address_space(1))) unsigned*)(A + (size_t)(bm + sr) * DD + k0 + sk),
            (__attribute__((address_space(3))) unsigned*)&As[tid * 8], 16, 0, 0);
        __builtin_amdgcn_global_load_lds(
            (const __attribute__((address_space(1))) unsigned*)(W + (size_t)(bn + sr) * DD + k0 + sk),
            (__attribute__((address_space(3))) unsigned*)&Bs[tid * 8], 16, 0, 0);
        __syncthreads();

        bf16x8 af[4], bfr[2];
#pragma unroll
        for (int f = 0; f < 4; ++f)
            af[f] = *(const bf16x8*)&As[(wm * 64 + f * 16 + lr) * TK + kq * 8];
#pragma unroll
        for (int g = 0; g < 2; ++g)
            bfr[g] = *(const bf16x8*)&Bs[(wn * 32 + g * 16 + lr) * TK + kq * 8];
#pragma unroll
        for (int fm = 0; fm < 4; ++fm)
#pragma unroll
            for (int fn = 0; fn < 2; ++fn)
                acc[fm][fn] = __builtin_amdgcn_mfma_f32_16x16x32_bf16(
                    af[fm], bfr[fn], acc[fm][fn], 0, 0, 0);
        __syncthreads();
    }

#pragma unroll
    for (int fm = 0; fm < 4; ++fm) {
        int row0 = bm + wm * 64 + fm * 16 + kq * 4;
#pragma unroll
        for (int fn = 0; fn < 2; ++fn) {
            int col = bn + wn * 32 + fn * 16 + lr;
            float bv_ = bias[col];
#pragma unroll
            for (int j = 0; j < 4; ++j)
                C[(size_t)(row0 + j) * DD + col] = f2bf(acc[fm][fn][j] + bv_);
        }
    }
}

// ---------------------------------------------------------------------------
// Output GEMM with fused split-KV merge. 64x128 tile, BK=64, 512 thr (8 waves
// 2Mx4N, each 32x32). A-tile built in-register from Op/Mp/Lp partials
// (merge formula) + ds_write_b128; B staged via global_load_lds.
// out = merged_ctx @ wo.T + bo (f32).
// ---------------------------------------------------------------------------
#define OM 64
#define ON 128
#define OK 64

__global__ __launch_bounds__(512) void k_gemm_out_fused(
    const short* __restrict__ Op, const float* __restrict__ Mp,
    const float* __restrict__ Lp, const short* __restrict__ W,
    const float* __restrict__ bias, float* __restrict__ C) {
    __shared__ __align__(16) short As[OM * OK];   // 8 KB
    __shared__ __align__(16) short Bs[ON * OK];   // 16 KB
    const int bm = blockIdx.y * OM;
    const int bn = blockIdx.x * ON;
    const int tid = threadIdx.x;
    const int lane = tid & 63;
    const int wid = tid >> 6;
    const int wm = wid & 1;
    const int wn = wid >> 1;
    const int lr = lane & 15;
    const int kq = lane >> 4;

    // A staging coords: row ar (0..63), d-chunk d0 (0,8,..,56)
    const int ar = tid >> 3;
    const int d0 = (tid & 7) << 3;
    const int grow = bm + ar;
    const int b = grow >> 10;
    const int s = grow & 1023;

    f32x4 acc[2][2];
#pragma unroll
    for (int i = 0; i < 2; ++i)
#pragma unroll
        for (int j = 0; j < 2; ++j) acc[i][j] = (f32x4)0.0f;

    for (int k0 = 0; k0 < DD; k0 += OK) {
        // ---- B tiles: 2 x global_load_lds per thread ----
#pragma unroll
        for (int i = 0; i < 2; ++i) {
            int t2 = i * 512 + tid;
            int br = t2 >> 3;
            int bk = (t2 & 7) << 3;
            __builtin_amdgcn_global_load_lds(
                (const __attribute__((address_space(1))) unsigned*)(W + (size_t)(bn + br) * DD + k0 + bk),
                (__attribute__((address_space(3))) unsigned*)&Bs[t2 * 8], 16, 0, 0);
        }
        // ---- A tile: merge Op halves for head h = k0>>6 ----
        {
            int hh = k0 >> 6;
            int hrow = ((b * HH + hh) << 10) + s;
            float m1 = Mp[hrow], m2 = Mp[NROW + hrow];
            float l1 = Lp[hrow], l2 = Lp[NROW + hrow];
            float m = fmaxf(m1, m2);
            float a1 = __expf(m1 - m), a2 = __expf(m2 - m);
            float inv = 1.0f / (l1 * a1 + l2 * a2);
            float c1 = a1 * inv, c2 = a2 * inv;
            bf16x8 o1 = *(const bf16x8*)&Op[(size_t)hrow * HDD + d0];
            bf16x8 o2 = *(const bf16x8*)&Op[((size_t)NROW + hrow) * HDD + d0];
            bf16x8 av;
#pragma unroll
            for (int e = 0; e < 8; ++e)
                av[e] = f2bf(bf2f(o1[e]) * c1 + bf2f(o2[e]) * c2);
            *(bf16x8*)&As[tid * 8] = av;
        }
        __syncthreads();

        bf16x8 af[2][2], bfr[2][2];
#pragma unroll
        for (int f = 0; f < 2; ++f)
#pragma unroll
            for (int ks = 0; ks < 2; ++ks) {
                af[f][ks] = *(const bf16x8*)&As[(wm * 32 + f * 16 + lr) * OK + ks * 32 + kq * 8];
                bfr[f][ks] = *(const bf16x8*)&Bs[(wn * 32 + f * 16 + lr) * OK + ks * 32 + kq * 8];
            }
#pragma unroll
        for (int fm = 0; fm < 2; ++fm)
#pragma unroll
            for (int fn = 0; fn < 2; ++fn)
#pragma unroll
                for (int ks = 0; ks < 2; ++ks)
                    acc[fm][fn] = __builtin_amdgcn_mfma_f32_16x16x32_bf16(
                        af[fm][ks], bfr[fn][ks], acc[fm][fn], 0, 0, 0);
        __syncthreads();
    }

#pragma unroll
    for (int fm = 0; fm < 2; ++fm) {
        int row0 = bm + wm * 32 + fm * 16 + kq * 4;
#pragma unroll
        for (int fn = 0; fn < 2; ++fn) {
            int col = bn + wn * 32 + fn * 16 + lr;
            float bv_ = bias[col];
#pragma unroll
            for (int j = 0; j < 4; ++j)
                C[(size_t)(row0 + j) * DD + col] = acc[fm][fn][j] + bv_;
        }
    }
}

// ---------------------------------------------------------------------------
// V [B,S,D] (head slice) -> V^T [B*H][HDD][SS]  via LDS 64x64 tiles
// ---------------------------------------------------------------------------
__global__ __launch_bounds__(256) void k_transpose_v(const short* __restrict__ vb,
                                                     short* __restrict__ vt) {
    __shared__ short T[64][64 + 2];
    const int s0 = blockIdx.x << 6;
    const int bh = blockIdx.y;
    const int b = bh >> 4, h = bh & 15;
    const int tid = threadIdx.x;
    const short* src = vb + ((size_t)(b * SS + s0)) * DD + h * HDD;
#pragma unroll
    for (int i = 0; i < 2; ++i) {
        int t = i * 256 + tid;
        int s = t >> 3, dc = (t & 7) << 3;
        bf16x8 val = *(const bf16x8*)(src + (size_t)s * DD + dc);
#pragma unroll
        for (int e = 0; e < 8; ++e) T[s][dc + e] = val[e];
    }
    __syncthreads();
    short* dst = vt + (size_t)bh * HDD * SS + s0;   // [d][s]
#pragma unroll
    for (int i = 0; i < 2; ++i) {
        int t = i * 256 + tid;
        int d = t >> 3, sc = (t & 7) << 3;
        bf16x8 o;
#pragma unroll
        for (int e = 0; e < 8; ++e) o[e] = T[sc + e][d];
        *(bf16x8*)(dst + (size_t)d * SS + sc) = o;
    }
}

// ---------------------------------------------------------------------------
// MFMA flash attention, swapped-QK^T 32x32 design, split-KV x2 (unchanged R6).
// ---------------------------------------------------------------------------
__global__ __launch_bounds__(256) void k_attn(
    const short* __restrict__ qb, const short* __restrict__ kb,
    const short* __restrict__ vt, const float* __restrict__ mask,
    short* __restrict__ Op, float* __restrict__ Mp, float* __restrict__ Lp) {
    __shared__ __align__(16) short Kls[2][64 * 64];
    __shared__ __align__(16) short Vls[2][64 * 64];

    const int bh = blockIdx.y;
    const int b = bh >> 4;
    const int h = bh & 15;
    const int q0 = blockIdx.x << 7;      // 128 q-rows per block
    const int kvh = blockIdx.z;
    const int tbase = kvh << 9;          // 0 or 512
    const int tid = threadIdx.x;
    const int lane = tid & 63;
    const int w = tid >> 6;
    const int ql = lane & 31;
    const int hi = lane >> 5;
    const int rsw = ql & 7;
    const float scale = 0.125f;

    const short* khead = kb + (size_t)b * SS * DD + h * HDD;   // + kv*DD + d
    const short* vhead = vt + (size_t)bh * HDD * SS;           // + d*SS + kv
    const float* maskp = mask + b * SS;

    bf16x8 qf0, qf1, qf2, qf3;
    {
        const short* qrow = qb + ((size_t)(b * SS + q0 + w * 32 + ql)) * DD + h * HDD + hi * 8;
        qf0 = *(const bf16x8*)(qrow);
        qf1 = *(const bf16x8*)(qrow + 16);
        qf2 = *(const bf16x8*)(qrow + 32);
        qf3 = *(const bf16x8*)(qrow + 48);
    }

    auto stage = [&](int t0, int bi) {
        const short* kbase = khead + (size_t)t0 * DD;
        const short* vbase = vhead + t0;
#pragma unroll
        for (int i = 0; i < 2; ++i) {
            int t = i * 256 + tid;
            int r = t >> 3;
            int cs = (t & 7) ^ (r & 7);
            __builtin_amdgcn_global_load_lds(
                (const __attribute__((address_space(1))) unsigned*)(kbase + (size_t)r * DD + cs * 8),
                (__attribute__((address_space(3))) unsigned*)&Kls[bi][t * 8], 16, 0, 0);
            __builtin_amdgcn_global_load_lds(
                (const __attribute__((address_space(1))) unsigned*)(vbase + (size_t)r * SS + cs * 8),
                (__attribute__((address_space(3))) unsigned*)&Vls[bi][t * 8], 16, 0, 0);
        }
    };

    float m_r = -3.0e38f, l_r = 0.0f;
    f32x16 O0 = (f32x16)0.0f, O1 = (f32x16)0.0f;

    auto body = [&](int t0, int cur) {
        const short* Kb = &Kls[cur][0];
        const short* Vb = &Vls[cur][0];

        f32x16 s0 = (f32x16)0.0f, s1 = (f32x16)0.0f;
        __builtin_amdgcn_s_setprio(1);
#pragma unroll
        for (int step = 0; step < 4; ++step) {
            int cpos = ((step << 1) | hi) ^ rsw;
            bf16x8 k0 = *(const bf16x8*)&Kb[ql * 64 + (cpos << 3)];
            bf16x8 k1 = *(const bf16x8*)&Kb[(32 + ql) * 64 + (cpos << 3)];
            bf16x8 qf = (step == 0) ? qf0 : (step == 1) ? qf1 : (step == 2) ? qf2 : qf3;
            s0 = __builtin_amdgcn_mfma_f32_32x32x16_bf16(k0, qf, s0, 0, 0, 0);
            s1 = __builtin_amdgcn_mfma_f32_32x32x16_bf16(k1, qf, s1, 0, 0, 0);
        }
        __builtin_amdgcn_s_setprio(0);

#pragma unroll
        for (int g = 0; g < 4; ++g) {
            float4 a4 = *(const float4*)&maskp[t0 + 8 * g + 4 * hi];
            float4 b4 = *(const float4*)&maskp[t0 + 32 + 8 * g + 4 * hi];
            s0[4 * g + 0] = fmaf(s0[4 * g + 0], scale, (1.0f - a4.x) * MASK_VAL);
            s0[4 * g + 1] = fmaf(s0[4 * g + 1], scale, (1.0f - a4.y) * MASK_VAL);
            s0[4 * g + 2] = fmaf(s0[4 * g + 2], scale, (1.0f - a4.z) * MASK_VAL);
            s0[4 * g + 3] = fmaf(s0[4 * g + 3], scale, (1.0f - a4.w) * MASK_VAL);
            s1[4 * g + 0] = fmaf(s1[4 * g + 0], scale, (1.0f - b4.x) * MASK_VAL);
            s1[4 * g + 1] = fmaf(s1[4 * g + 1], scale, (1.0f - b4.y) * MASK_VAL);
            s1[4 * g + 2] = fmaf(s1[4 * g + 2], scale, (1.0f - b4.z) * MASK_VAL);
            s1[4 * g + 3] = fmaf(s1[4 * g + 3], scale, (1.0f - b4.w) * MASK_VAL);
        }

        float mt[16];
#pragma unroll
        for (int r = 0; r < 16; ++r) mt[r] = fmaxf(s0[r], s1[r]);
#pragma unroll
        for (int st = 8; st > 0; st >>= 1)
#pragma unroll
            for (int r = 0; r < 8; ++r)
                if (r < st) mt[r] = fmaxf(mt[r], mt[r + st]);
        float mx = fmaxf(mt[0], __shfl_xor(mt[0], 32));

        bool need = mx > m_r + 8.0f;
        if (__any(need)) {
            float mn = fmaxf(m_r, mx);
            float alpha = __expf(m_r - mn);
            m_r = mn;
            l_r *= alpha;
#pragma unroll
            for (int r = 0; r < 16; ++r) {
                int qrow = (r & 3) + 8 * (r >> 2) + 4 * hi;
                float al = __shfl(alpha, qrow, 64);
                O0[r] *= al;
                O1[r] *= al;
            }
        }

        float st0[16];
#pragma unroll
        for (int r = 0; r < 16; ++r) {
            s0[r] = __expf(s0[r] - m_r);
            s1[r] = __expf(s1[r] - m_r);
            st0[r] = s0[r] + s1[r];
        }
#pragma unroll
        for (int st = 8; st > 0; st >>= 1)
#pragma unroll
            for (int r = 0; r < 8; ++r)
                if (r < st) st0[r] += st0[r + st];
        l_r += st0[0] + __shfl_xor(st0[0], 32);

        unsigned w0 = cvt_pk_bf16(s0[0], s0[1]),  w1 = cvt_pk_bf16(s0[2], s0[3]);
        unsigned w2 = cvt_pk_bf16(s0[4], s0[5]),  w3 = cvt_pk_bf16(s0[6], s0[7]);
        unsigned w4 = cvt_pk_bf16(s0[8], s0[9]),  w5 = cvt_pk_bf16(s0[10], s0[11]);
        unsigned w6 = cvt_pk_bf16(s0[12], s0[13]), w7 = cvt_pk_bf16(s0[14], s0[15]);
        plane32_swap(w0, w2); plane32_swap(w1, w3);
        plane32_swap(w4, w6); plane32_swap(w5, w7);
        uint4v f0 = {w0, w1, w2, w3};
        uint4v f1 = {w4, w5, w6, w7};
        unsigned x0 = cvt_pk_bf16(s1[0], s1[1]),  x1 = cvt_pk_bf16(s1[2], s1[3]);
        unsigned x2 = cvt_pk_bf16(s1[4], s1[5]),  x3 = cvt_pk_bf16(s1[6], s1[7]);
        unsigned x4 = cvt_pk_bf16(s1[8], s1[9]),  x5 = cvt_pk_bf16(s1[10], s1[11]);
        unsigned x6 = cvt_pk_bf16(s1[12], s1[13]), x7 = cvt_pk_bf16(s1[14], s1[15]);
        plane32_swap(x0, x2); plane32_swap(x1, x3);
        plane32_swap(x4, x6); plane32_swap(x5, x7);
        uint4v f2 = {x0, x1, x2, x3};
        uint4v f3 = {x4, x5, x6, x7};

        bf16x8 pf0 = __builtin_bit_cast(bf16x8, f0);
        bf16x8 pf1 = __builtin_bit_cast(bf16x8, f1);
        bf16x8 pf2 = __builtin_bit_cast(bf16x8, f2);
        bf16x8 pf3 = __builtin_bit_cast(bf16x8, f3);

        __builtin_amdgcn_s_setprio(1);
#pragma unroll
        for (int ks = 0; ks < 4; ++ks) {
            int cpos = ((ks << 1) | hi) ^ rsw;
            bf16x8 pf = (ks == 0) ? pf0 : (ks == 1) ? pf1 : (ks == 2) ? pf2 : pf3;
            bf16x8 v0 = *(const bf16x8*)&Vb[ql * 64 + (cpos << 3)];
            bf16x8 v1 = *(const bf16x8*)&Vb[(32 + ql) * 64 + (cpos << 3)];
            O0 = __builtin_amdgcn_mfma_f32_32x32x16_bf16(pf, v0, O0, 0, 0, 0);
            O1 = __builtin_amdgcn_mfma_f32_32x32x16_bf16(pf, v1, O1, 0, 0, 0);
        }
        __builtin_amdgcn_s_setprio(0);
    };

    stage(tbase, 0);
    for (int it = 0; it < 7; ++it) {
        stage(tbase + ((it + 1) << 6), (it + 1) & 1);
        asm volatile("s_waitcnt vmcnt(4)\n\ts_barrier" ::: "memory");
        body(tbase + (it << 6), it & 1);
        asm volatile("s_barrier" ::: "memory");
    }
    asm volatile("s_waitcnt vmcnt(0)\n\ts_barrier" ::: "memory");
    body(tbase + (7 << 6), 1);

    const int rowb = bh * SS + q0 + w * 32;
    short* ob = Op + ((size_t)kvh * NROW + rowb) * HDD;
#pragma unroll
    for (int r = 0; r < 16; ++r) {
        int qrow = (r & 3) + 8 * (r >> 2) + 4 * hi;
        ob[(size_t)qrow * HDD + ql] = f2bf(O0[r]);
        ob[(size_t)qrow * HDD + 32 + ql] = f2bf(O1[r]);
    }
    if (lane < 32) {
        Mp[kvh * NROW + rowb + lane] = m_r;
        Lp[kvh * NROW + rowb + lane] = l_r;
    }
}

// ---------------------------------------------------------------------------
extern "C" void kernel_launch(void* const* d_in, const int* in_sizes, int n_in,
                              void* d_out, int out_size, void* d_ws, size_t ws_size,
                              hipStream_t stream) {
    const float* h    = (const float*)d_in[0];
    const float* mask = (const float*)d_in[1];
    const float* wq   = (const float*)d_in[2];
    const float* bq   = (const float*)d_in[3];
    const float* wk   = (const float*)d_in[4];
    const float* bk   = (const float*)d_in[5];
    const float* wv   = (const float*)d_in[6];
    const float* bv   = (const float*)d_in[7];
    const float* wo   = (const float*)d_in[8];
    const float* bo   = (const float*)d_in[9];
    float* out = (float*)d_out;

    char* base = (char*)d_ws;
    short* x_bf  = (short*)base;                       // 4 MB @ 0
    short* w_bf  = (short*)(base + (4u << 20));        // 8 MB @ 4
    short* q_bf  = (short*)(base + (12u << 20));       // 4 MB @ 12
    short* k_bf  = (short*)(base + (16u << 20));       // 4 MB @ 16
    short* v_bf  = (short*)(base + (20u << 20));       // 4 MB @ 20
    short* v_t   = (short*)(base + (24u << 20));       // 4 MB @ 24
    short* Op    = (short*)(base + (32u << 20));       // 8 MB @ 32
    float* Mp    = (float*)(base + (40u << 20));       // 256 KB
    float* Lp    = (float*)(base + (40u << 20) + (NROW * 2 * sizeof(float)));

    k_prep<<<dim3(1024, 1, 5), 256, 0, stream>>>(h, wq, wk, wv, wo, x_bf, w_bf);

    dim3 gqkv(DD / TN, BB * SS / TM, 3);
    k_gemm_qkv<<<gqkv, 512, 0, stream>>>(x_bf, w_bf, bq, bk, bv, q_bf, k_bf, v_bf);

    dim3 gtr(SS / 64, BB * HH);
    k_transpose_v<<<gtr, 256, 0, stream>>>(v_bf, v_t);

    dim3 gattn(SS / 128, BB * HH, 2);
    k_attn<<<gattn, 256, 0, stream>>>(q_bf, k_bf, v_t, mask, Op, Mp, Lp);

    dim3 gout(DD / ON, BB * SS / OM);
    k_gemm_out_fused<<<gout, 512, 0, stream>>>(Op, Mp, Lp, w_bf + (size_t)3 * DD * DD, bo, out);
}

// Round 8
// 82.557 us; speedup vs baseline: 1.4827x; 1.0369x over previous
//
#include <hip/hip_runtime.h>
#include <hip/hip_bf16.h>

#define BB 2
#define SS 1024
#define DD 1024
#define HH 16
#define HDD 64
#define MASK_VAL -10000.0f
#define BSD (BB * SS * DD)   // 2097152
#define NROW (BB * HH * SS)  // 32768 (bh*1024 + qrow)

typedef __attribute__((ext_vector_type(8))) short bf16x8;
typedef __attribute__((ext_vector_type(4))) short short4v;
typedef __attribute__((ext_vector_type(4))) float f32x4;
typedef __attribute__((ext_vector_type(16))) float f32x16;
typedef __attribute__((ext_vector_type(4))) unsigned int uint4v;

__device__ __forceinline__ short f2bf(float f) {
    union { float f; unsigned u; } v; v.f = f;
    unsigned r = v.u + 0x7FFFu + ((v.u >> 16) & 1u);   // RN-even
    return (short)(r >> 16);
}
__device__ __forceinline__ float bf2f(short s) {
    union { unsigned u; float f; } v;
    v.u = ((unsigned)(unsigned short)s) << 16;
    return v.f;
}
__device__ __forceinline__ unsigned cvt_pk_bf16(float lo, float hi) {
    unsigned r;
    asm("v_cvt_pk_bf16_f32 %0, %1, %2" : "=v"(r) : "v"(lo), "v"(hi));
    return r;
}
__device__ __forceinline__ void plane32_swap(unsigned& a, unsigned& b) {
#if __has_builtin(__builtin_amdgcn_permlane32_swap)
    auto r = __builtin_amdgcn_permlane32_swap(a, b, false, false);
    a = r[0]; b = r[1];
#else
    unsigned as = (unsigned)__shfl_xor((int)a, 32);
    unsigned bs = (unsigned)__shfl_xor((int)b, 32);
    bool lo = ((threadIdx.x & 63) < 32);
    unsigned na = lo ? a : bs;
    unsigned nb = lo ? as : b;
    a = na; b = nb;
#endif
}

// ---------------------------------------------------------------------------
// fused prep: z=0 -> x_bf = bf16(h0+h1); z=1..4 -> weight z-1 to bf16
// ---------------------------------------------------------------------------
__global__ __launch_bounds__(256) void k_prep(
    const float* __restrict__ h,
    const float* __restrict__ wq, const float* __restrict__ wk,
    const float* __restrict__ wv, const float* __restrict__ wo,
    short* __restrict__ xbf, short* __restrict__ wbf) {
    int z = blockIdx.z;
    int i = blockIdx.x * 256 + threadIdx.x;
    if (z == 0) {
        const float4* h0 = (const float4*)h;
        const float4* h1 = (const float4*)(h + (size_t)BSD);
        float4 a0 = h0[2 * i], a1 = h0[2 * i + 1];
        float4 b0 = h1[2 * i], b1 = h1[2 * i + 1];
        bf16x8 o;
        o[0] = f2bf(a0.x + b0.x); o[1] = f2bf(a0.y + b0.y);
        o[2] = f2bf(a0.z + b0.z); o[3] = f2bf(a0.w + b0.w);
        o[4] = f2bf(a1.x + b1.x); o[5] = f2bf(a1.y + b1.y);
        o[6] = f2bf(a1.z + b1.z); o[7] = f2bf(a1.w + b1.w);
        ((bf16x8*)xbf)[i] = o;
    } else {
        if (blockIdx.x >= 512) return;
        const float* src = (z == 1) ? wq : (z == 2) ? wk : (z == 3) ? wv : wo;
        short* dst = wbf + (size_t)(z - 1) * (DD * DD);
        const float4* s4 = (const float4*)src;
        float4 a0 = s4[2 * i], a1 = s4[2 * i + 1];
        bf16x8 o;
        o[0] = f2bf(a0.x); o[1] = f2bf(a0.y); o[2] = f2bf(a0.z); o[3] = f2bf(a0.w);
        o[4] = f2bf(a1.x); o[5] = f2bf(a1.y); o[6] = f2bf(a1.z); o[7] = f2bf(a1.w);
        ((bf16x8*)dst)[i] = o;
    }
}

// ---------------------------------------------------------------------------
// QKV bf16 MFMA GEMM, 128x64 tile, BK=32, 256 threads (4 waves, 2Mx2N,
// each wave 64x32 = 4x2 frags). grid 16x16x3 = 768 blocks = 3/CU balanced.
// z=0,1 -> bf16 out [B,S,D] + bias; z=2 -> V^T out [B*H][64][S] + bias.
// ---------------------------------------------------------------------------
#define QBM 128
#define QBN 64
#define QBK 32

__global__ __launch_bounds__(256) void k_gemm_qkv(
    const short* __restrict__ xbf, const short* __restrict__ wbf,
    const float* __restrict__ bq, const float* __restrict__ bk,
    const float* __restrict__ bv,
    short* __restrict__ qb, short* __restrict__ kb, short* __restrict__ vt) {
    __shared__ __align__(16) short As[QBM * QBK];   // 8 KB
    __shared__ __align__(16) short Bs[QBN * QBK];   // 4 KB
    const int z = blockIdx.z;
    const short* W = wbf + (size_t)z * (DD * DD);
    const float* bias = (z == 0) ? bq : (z == 1) ? bk : bv;
    const int bm = blockIdx.y * QBM;
    const int bn = blockIdx.x * QBN;
    const int tid = threadIdx.x;
    const int lane = tid & 63;
    const int wid = tid >> 6;
    const int wm = wid >> 1;          // 0..1: M 64-half
    const int wn = wid & 1;           // 0..1: N 32-half
    const int lr = lane & 15;
    const int kq = lane >> 4;

    f32x4 acc[4][2];
#pragma unroll
    for (int i = 0; i < 4; ++i)
#pragma unroll
        for (int j = 0; j < 2; ++j) acc[i][j] = (f32x4)0.0f;

    for (int k0 = 0; k0 < DD; k0 += QBK) {
#pragma unroll
        for (int i = 0; i < 2; ++i) {
            int s = i * 256 + tid;
            int r = s >> 2;
            int kc = (s & 3) << 3;
            __builtin_amdgcn_global_load_lds(
                (const __attribute__((address_space(1))) unsigned*)(xbf + (size_t)(bm + r) * DD + k0 + kc),
                (__attribute__((address_space(3))) unsigned*)&As[s * 8], 16, 0, 0);
        }
        {
            int r = tid >> 2;
            int kc = (tid & 3) << 3;
            __builtin_amdgcn_global_load_lds(
                (const __attribute__((address_space(1))) unsigned*)(W + (size_t)(bn + r) * DD + k0 + kc),
                (__attribute__((address_space(3))) unsigned*)&Bs[tid * 8], 16, 0, 0);
        }
        __syncthreads();

        bf16x8 af[4], bfr[2];
#pragma unroll
        for (int f = 0; f < 4; ++f)
            af[f] = *(const bf16x8*)&As[(wm * 64 + f * 16 + lr) * QBK + kq * 8];
#pragma unroll
        for (int g = 0; g < 2; ++g)
            bfr[g] = *(const bf16x8*)&Bs[(wn * 32 + g * 16 + lr) * QBK + kq * 8];
#pragma unroll
        for (int fm = 0; fm < 4; ++fm)
#pragma unroll
            for (int fn = 0; fn < 2; ++fn)
                acc[fm][fn] = __builtin_amdgcn_mfma_f32_16x16x32_bf16(
                    af[fm], bfr[fn], acc[fm][fn], 0, 0, 0);
        __syncthreads();
    }

    // epilogue. C/D layout: col = lane&15, row = (lane>>4)*4 + reg.
    if (z < 2) {
        short* C = (z == 0) ? qb : kb;
#pragma unroll
        for (int fm = 0; fm < 4; ++fm) {
            int row0 = bm + wm * 64 + fm * 16 + kq * 4;
#pragma unroll
            for (int fn = 0; fn < 2; ++fn) {
                int col = bn + wn * 32 + fn * 16 + lr;
                float bv_ = bias[col];
#pragma unroll
                for (int j = 0; j < 4; ++j)
                    C[(size_t)(row0 + j) * DD + col] = f2bf(acc[fm][fn][j] + bv_);
            }
        }
    } else {
        // V^T: [B][H][64][S]; the 4 regs are contiguous in S
#pragma unroll
        for (int fm = 0; fm < 4; ++fm) {
            int row0 = bm + wm * 64 + fm * 16 + kq * 4;
            int bidx = row0 >> 10, s0 = row0 & 1023;
#pragma unroll
            for (int fn = 0; fn < 2; ++fn) {
                int col = bn + wn * 32 + fn * 16 + lr;
                float bv_ = bias[col];
                size_t addr = ((size_t)(bidx * HH + (col >> 6)) * HDD + (col & 63)) * SS + s0;
                short4v o;
                o.x = f2bf(acc[fm][fn][0] + bv_); o.y = f2bf(acc[fm][fn][1] + bv_);
                o.z = f2bf(acc[fm][fn][2] + bv_); o.w = f2bf(acc[fm][fn][3] + bv_);
                *(short4v*)&vt[addr] = o;
            }
        }
    }
}

// ---------------------------------------------------------------------------
// Output GEMM with fused split-KV merge (unchanged from R7).
// ---------------------------------------------------------------------------
#define OM 64
#define ON 128
#define OK 64

__global__ __launch_bounds__(512) void k_gemm_out_fused(
    const short* __restrict__ Op, const float* __restrict__ Mp,
    const float* __restrict__ Lp, const short* __restrict__ W,
    const float* __restrict__ bias, float* __restrict__ C) {
    __shared__ __align__(16) short As[OM * OK];   // 8 KB
    __shared__ __align__(16) short Bs[ON * OK];   // 16 KB
    const int bm = blockIdx.y * OM;
    const int bn = blockIdx.x * ON;
    const int tid = threadIdx.x;
    const int lane = tid & 63;
    const int wid = tid >> 6;
    const int wm = wid & 1;
    const int wn = wid >> 1;
    const int lr = lane & 15;
    const int kq = lane >> 4;

    const int ar = tid >> 3;
    const int d0 = (tid & 7) << 3;
    const int grow = bm + ar;
    const int b = grow >> 10;
    const int s = grow & 1023;

    f32x4 acc[2][2];
#pragma unroll
    for (int i = 0; i < 2; ++i)
#pragma unroll
        for (int j = 0; j < 2; ++j) acc[i][j] = (f32x4)0.0f;

    for (int k0 = 0; k0 < DD; k0 += OK) {
#pragma unroll
        for (int i = 0; i < 2; ++i) {
            int t2 = i * 512 + tid;
            int br = t2 >> 3;
            int bk = (t2 & 7) << 3;
            __builtin_amdgcn_global_load_lds(
                (const __attribute__((address_space(1))) unsigned*)(W + (size_t)(bn + br) * DD + k0 + bk),
                (__attribute__((address_space(3))) unsigned*)&Bs[t2 * 8], 16, 0, 0);
        }
        {
            int hh = k0 >> 6;
            int hrow = ((b * HH + hh) << 10) + s;
            float m1 = Mp[hrow], m2 = Mp[NROW + hrow];
            float l1 = Lp[hrow], l2 = Lp[NROW + hrow];
            float m = fmaxf(m1, m2);
            float a1 = __expf(m1 - m), a2 = __expf(m2 - m);
            float inv = 1.0f / (l1 * a1 + l2 * a2);
            float c1 = a1 * inv, c2 = a2 * inv;
            bf16x8 o1 = *(const bf16x8*)&Op[(size_t)hrow * HDD + d0];
            bf16x8 o2 = *(const bf16x8*)&Op[((size_t)NROW + hrow) * HDD + d0];
            bf16x8 av;
#pragma unroll
            for (int e = 0; e < 8; ++e)
                av[e] = f2bf(bf2f(o1[e]) * c1 + bf2f(o2[e]) * c2);
            *(bf16x8*)&As[tid * 8] = av;
        }
        __syncthreads();

        bf16x8 af[2][2], bfr[2][2];
#pragma unroll
        for (int f = 0; f < 2; ++f)
#pragma unroll
            for (int ks = 0; ks < 2; ++ks) {
                af[f][ks] = *(const bf16x8*)&As[(wm * 32 + f * 16 + lr) * OK + ks * 32 + kq * 8];
                bfr[f][ks] = *(const bf16x8*)&Bs[(wn * 32 + f * 16 + lr) * OK + ks * 32 + kq * 8];
            }
#pragma unroll
        for (int fm = 0; fm < 2; ++fm)
#pragma unroll
            for (int fn = 0; fn < 2; ++fn)
#pragma unroll
                for (int ks = 0; ks < 2; ++ks)
                    acc[fm][fn] = __builtin_amdgcn_mfma_f32_16x16x32_bf16(
                        af[fm][ks], bfr[fn][ks], acc[fm][fn], 0, 0, 0);
        __syncthreads();
    }

#pragma unroll
    for (int fm = 0; fm < 2; ++fm) {
        int row0 = bm + wm * 32 + fm * 16 + kq * 4;
#pragma unroll
        for (int fn = 0; fn < 2; ++fn) {
            int col = bn + wn * 32 + fn * 16 + lr;
            float bv_ = bias[col];
#pragma unroll
            for (int j = 0; j < 4; ++j)
                C[(size_t)(row0 + j) * DD + col] = acc[fm][fn][j] + bv_;
        }
    }
}

// ---------------------------------------------------------------------------
// MFMA flash attention, swapped-QK^T 32x32, split-KV x2, with split K/V waits:
// stage issues K,K,V,V; vmcnt(6)+bar before QK^T (K ready), vmcnt(4)+bar
// before PV (V ready) -> V landing overlaps QK^T+softmax.
// ---------------------------------------------------------------------------
__global__ __launch_bounds__(256) void k_attn(
    const short* __restrict__ qb, const short* __restrict__ kb,
    const short* __restrict__ vt, const float* __restrict__ mask,
    short* __restrict__ Op, float* __restrict__ Mp, float* __restrict__ Lp) {
    __shared__ __align__(16) short Kls[2][64 * 64];
    __shared__ __align__(16) short Vls[2][64 * 64];

    const int bh = blockIdx.y;
    const int b = bh >> 4;
    const int h = bh & 15;
    const int q0 = blockIdx.x << 7;
    const int kvh = blockIdx.z;
    const int tbase = kvh << 9;
    const int tid = threadIdx.x;
    const int lane = tid & 63;
    const int w = tid >> 6;
    const int ql = lane & 31;
    const int hi = lane >> 5;
    const int rsw = ql & 7;
    const float scale = 0.125f;

    const short* khead = kb + (size_t)b * SS * DD + h * HDD;
    const short* vhead = vt + (size_t)bh * HDD * SS;
    const float* maskp = mask + b * SS;

    bf16x8 qf0, qf1, qf2, qf3;
    {
        const short* qrow = qb + ((size_t)(b * SS + q0 + w * 32 + ql)) * DD + h * HDD + hi * 8;
        qf0 = *(const bf16x8*)(qrow);
        qf1 = *(const bf16x8*)(qrow + 16);
        qf2 = *(const bf16x8*)(qrow + 32);
        qf3 = *(const bf16x8*)(qrow + 48);
    }

    auto stage = [&](int t0, int bi) {
        const short* kbase = khead + (size_t)t0 * DD;
        const short* vbase = vhead + t0;
#pragma unroll
        for (int i = 0; i < 2; ++i) {
            int t = i * 256 + tid;
            int r = t >> 3;
            int cs = (t & 7) ^ (r & 7);
            __builtin_amdgcn_global_load_lds(
                (const __attribute__((address_space(1))) unsigned*)(kbase + (size_t)r * DD + cs * 8),
                (__attribute__((address_space(3))) unsigned*)&Kls[bi][t * 8], 16, 0, 0);
        }
#pragma unroll
        for (int i = 0; i < 2; ++i) {
            int t = i * 256 + tid;
            int r = t >> 3;
            int cs = (t & 7) ^ (r & 7);
            __builtin_amdgcn_global_load_lds(
                (const __attribute__((address_space(1))) unsigned*)(vbase + (size_t)r * SS + cs * 8),
                (__attribute__((address_space(3))) unsigned*)&Vls[bi][t * 8], 16, 0, 0);
        }
    };

    float m_r = -3.0e38f, l_r = 0.0f;
    f32x16 O0 = (f32x16)0.0f, O1 = (f32x16)0.0f;

    auto body = [&](int t0, int cur, int tail) {
        const short* Kb = &Kls[cur][0];
        const short* Vb = &Vls[cur][0];

        f32x16 s0 = (f32x16)0.0f, s1 = (f32x16)0.0f;
        __builtin_amdgcn_s_setprio(1);
#pragma unroll
        for (int step = 0; step < 4; ++step) {
            int cpos = ((step << 1) | hi) ^ rsw;
            bf16x8 k0 = *(const bf16x8*)&Kb[ql * 64 + (cpos << 3)];
            bf16x8 k1 = *(const bf16x8*)&Kb[(32 + ql) * 64 + (cpos << 3)];
            bf16x8 qf = (step == 0) ? qf0 : (step == 1) ? qf1 : (step == 2) ? qf2 : qf3;
            s0 = __builtin_amdgcn_mfma_f32_32x32x16_bf16(k0, qf, s0, 0, 0, 0);
            s1 = __builtin_amdgcn_mfma_f32_32x32x16_bf16(k1, qf, s1, 0, 0, 0);
        }
        __builtin_amdgcn_s_setprio(0);

#pragma unroll
        for (int g = 0; g < 4; ++g) {
            float4 a4 = *(const float4*)&maskp[t0 + 8 * g + 4 * hi];
            float4 b4 = *(const float4*)&maskp[t0 + 32 + 8 * g + 4 * hi];
            s0[4 * g + 0] = fmaf(s0[4 * g + 0], scale, (1.0f - a4.x) * MASK_VAL);
            s0[4 * g + 1] = fmaf(s0[4 * g + 1], scale, (1.0f - a4.y) * MASK_VAL);
            s0[4 * g + 2] = fmaf(s0[4 * g + 2], scale, (1.0f - a4.z) * MASK_VAL);
            s0[4 * g + 3] = fmaf(s0[4 * g + 3], scale, (1.0f - a4.w) * MASK_VAL);
            s1[4 * g + 0] = fmaf(s1[4 * g + 0], scale, (1.0f - b4.x) * MASK_VAL);
            s1[4 * g + 1] = fmaf(s1[4 * g + 1], scale, (1.0f - b4.y) * MASK_VAL);
            s1[4 * g + 2] = fmaf(s1[4 * g + 2], scale, (1.0f - b4.z) * MASK_VAL);
            s1[4 * g + 3] = fmaf(s1[4 * g + 3], scale, (1.0f - b4.w) * MASK_VAL);
        }

        float mt[16];
#pragma unroll
        for (int r = 0; r < 16; ++r) mt[r] = fmaxf(s0[r], s1[r]);
#pragma unroll
        for (int st = 8; st > 0; st >>= 1)
#pragma unroll
            for (int r = 0; r < 8; ++r)
                if (r < st) mt[r] = fmaxf(mt[r], mt[r + st]);
        float mx = fmaxf(mt[0], __shfl_xor(mt[0], 32));

        bool need = mx > m_r + 8.0f;
        if (__any(need)) {
            float mn = fmaxf(m_r, mx);
            float alpha = __expf(m_r - mn);
            m_r = mn;
            l_r *= alpha;
#pragma unroll
            for (int r = 0; r < 16; ++r) {
                int qrow = (r & 3) + 8 * (r >> 2) + 4 * hi;
                float al = __shfl(alpha, qrow, 64);
                O0[r] *= al;
                O1[r] *= al;
            }
        }

        float st0[16];
#pragma unroll
        for (int r = 0; r < 16; ++r) {
            s0[r] = __expf(s0[r] - m_r);
            s1[r] = __expf(s1[r] - m_r);
            st0[r] = s0[r] + s1[r];
        }
#pragma unroll
        for (int st = 8; st > 0; st >>= 1)
#pragma unroll
            for (int r = 0; r < 8; ++r)
                if (r < st) st0[r] += st0[r + st];
        l_r += st0[0] + __shfl_xor(st0[0], 32);

        unsigned w0 = cvt_pk_bf16(s0[0], s0[1]),  w1 = cvt_pk_bf16(s0[2], s0[3]);
        unsigned w2 = cvt_pk_bf16(s0[4], s0[5]),  w3 = cvt_pk_bf16(s0[6], s0[7]);
        unsigned w4 = cvt_pk_bf16(s0[8], s0[9]),  w5 = cvt_pk_bf16(s0[10], s0[11]);
        unsigned w6 = cvt_pk_bf16(s0[12], s0[13]), w7 = cvt_pk_bf16(s0[14], s0[15]);
        plane32_swap(w0, w2); plane32_swap(w1, w3);
        plane32_swap(w4, w6); plane32_swap(w5, w7);
        uint4v f0 = {w0, w1, w2, w3};
        uint4v f1 = {w4, w5, w6, w7};
        unsigned x0 = cvt_pk_bf16(s1[0], s1[1]),  x1 = cvt_pk_bf16(s1[2], s1[3]);
        unsigned x2 = cvt_pk_bf16(s1[4], s1[5]),  x3 = cvt_pk_bf16(s1[6], s1[7]);
        unsigned x4 = cvt_pk_bf16(s1[8], s1[9]),  x5 = cvt_pk_bf16(s1[10], s1[11]);
        unsigned x6 = cvt_pk_bf16(s1[12], s1[13]), x7 = cvt_pk_bf16(s1[14], s1[15]);
        plane32_swap(x0, x2); plane32_swap(x1, x3);
        plane32_swap(x4, x6); plane32_swap(x5, x7);
        uint4v f2 = {x0, x1, x2, x3};
        uint4v f3 = {x4, x5, x6, x7};

        bf16x8 pf0 = __builtin_bit_cast(bf16x8, f0);
        bf16x8 pf1 = __builtin_bit_cast(bf16x8, f1);
        bf16x8 pf2 = __builtin_bit_cast(bf16x8, f2);
        bf16x8 pf3 = __builtin_bit_cast(bf16x8, f3);

        // V(t) ready gate (all waves), then PV
        if (tail) { asm volatile("s_waitcnt vmcnt(0)\n\ts_barrier" ::: "memory"); }
        else      { asm volatile("s_waitcnt vmcnt(4)\n\ts_barrier" ::: "memory"); }

        __builtin_amdgcn_s_setprio(1);
#pragma unroll
        for (int ks = 0; ks < 4; ++ks) {
            int cpos = ((ks << 1) | hi) ^ rsw;
            bf16x8 pf = (ks == 0) ? pf0 : (ks == 1) ? pf1 : (ks == 2) ? pf2 : pf3;
            bf16x8 v0 = *(const bf16x8*)&Vb[ql * 64 + (cpos << 3)];
            bf16x8 v1 = *(const bf16x8*)&Vb[(32 + ql) * 64 + (cpos << 3)];
            O0 = __builtin_amdgcn_mfma_f32_32x32x16_bf16(pf, v0, O0, 0, 0, 0);
            O1 = __builtin_amdgcn_mfma_f32_32x32x16_bf16(pf, v1, O1, 0, 0, 0);
        }
        __builtin_amdgcn_s_setprio(0);
    };

    stage(tbase, 0);
    for (int it = 0; it < 7; ++it) {
        stage(tbase + ((it + 1) << 6), (it + 1) & 1);
        asm volatile("s_waitcnt vmcnt(6)\n\ts_barrier" ::: "memory");   // K(it) ready
        body(tbase + (it << 6), it & 1, 0);
        asm volatile("s_barrier" ::: "memory");                         // buf reuse guard
    }
    asm volatile("s_waitcnt vmcnt(2)\n\ts_barrier" ::: "memory");       // K(7) ready
    body(tbase + (7 << 6), 1, 1);

    const int rowb = bh * SS + q0 + w * 32;
    short* ob = Op + ((size_t)kvh * NROW + rowb) * HDD;
#pragma unroll
    for (int r = 0; r < 16; ++r) {
        int qrow = (r & 3) + 8 * (r >> 2) + 4 * hi;
        ob[(size_t)qrow * HDD + ql] = f2bf(O0[r]);
        ob[(size_t)qrow * HDD + 32 + ql] = f2bf(O1[r]);
    }
    if (lane < 32) {
        Mp[kvh * NROW + rowb + lane] = m_r;
        Lp[kvh * NROW + rowb + lane] = l_r;
    }
}

// ---------------------------------------------------------------------------
extern "C" void kernel_launch(void* const* d_in, const int* in_sizes, int n_in,
                              void* d_out, int out_size, void* d_ws, size_t ws_size,
                              hipStream_t stream) {
    const float* h    = (const float*)d_in[0];
    const float* mask = (const float*)d_in[1];
    const float* wq   = (const float*)d_in[2];
    const float* bq   = (const float*)d_in[3];
    const float* wk   = (const float*)d_in[4];
    const float* bk   = (const float*)d_in[5];
    const float* wv   = (const float*)d_in[6];
    const float* bv   = (const float*)d_in[7];
    const float* wo   = (const float*)d_in[8];
    const float* bo   = (const float*)d_in[9];
    float* out = (float*)d_out;

    char* base = (char*)d_ws;
    short* x_bf  = (short*)base;                       // 4 MB @ 0
    short* w_bf  = (short*)(base + (4u << 20));        // 8 MB @ 4
    short* q_bf  = (short*)(base + (12u << 20));       // 4 MB @ 12
    short* k_bf  = (short*)(base + (16u << 20));       // 4 MB @ 16
    short* v_t   = (short*)(base + (24u << 20));       // 4 MB @ 24
    short* Op    = (short*)(base + (32u << 20));       // 8 MB @ 32
    float* Mp    = (float*)(base + (40u << 20));       // 256 KB
    float* Lp    = (float*)(base + (40u << 20) + (NROW * 2 * sizeof(float)));

    k_prep<<<dim3(1024, 1, 5), 256, 0, stream>>>(h, wq, wk, wv, wo, x_bf, w_bf);

    dim3 gqkv(DD / QBN, BB * SS / QBM, 3);
    k_gemm_qkv<<<gqkv, 256, 0, stream>>>(x_bf, w_bf, bq, bk, bv, q_bf, k_bf, v_t);

    dim3 gattn(SS / 128, BB * HH, 2);
    k_attn<<<gattn, 256, 0, stream>>>(q_bf, k_bf, v_t, mask, Op, Mp, Lp);

    dim3 gout(DD / ON, BB * SS / OM);
    k_gemm_out_fused<<<gout, 512, 0, stream>>>(Op, Mp, Lp, w_bf + (size_t)3 * DD * DD, bo, out);
}